// Round 8
// baseline (4171.489 us; speedup 1.0000x reference)
//
#include <hip/hip_runtime.h>
#include <math.h>

typedef _Float16 half8 __attribute__((ext_vector_type(8)));
typedef _Float16 half4_t __attribute__((ext_vector_type(4)));
typedef float floatx16 __attribute__((ext_vector_type(16)));
typedef float float4_t __attribute__((ext_vector_type(4)));

#define NT 128
#define NB 64
#define NC 16
#define CL 8
#define NSQ 3   // W = U^(2^NSQ) = U^CL

// element index with 8-f16 (16B) unit XOR swizzle inside a 64-f16 (128B) row
__device__ __forceinline__ int eidx(int row, int col) {
  return row * 64 + ((((col >> 3) ^ row) & 7) << 3) + (col & 7);
}
__device__ __forceinline__ int jcolf(int j, int pblk, int hi) {
  return 32 * pblk + (j & 3) + 8 * (j >> 2) + 4 * hi;
}

// LDS-only barrier (globals never carry intra-kernel cross-wave data here)
#define BARX() do {                                        \
  asm volatile("s_waitcnt lgkmcnt(0)" ::: "memory");       \
  __builtin_amdgcn_s_barrier();                            \
  __builtin_amdgcn_sched_barrier(0);                       \
} while (0)

// ---------------- chunk scan: PASS3=false -> emit p_c ; PASS3=true -> emit out ----
template<bool PASS3>
__global__ __launch_bounds__(512, 8)
void qrnn_scan(const float* __restrict__ data_r, const float* __restrict__ data_i,
               const float* __restrict__ U_r, const float* __restrict__ U_i,
               const float* __restrict__ lam_p, float* __restrict__ out) {
  __shared__ __align__(16) _Float16 Vr[4096], Vi[4096];
  __shared__ __align__(16) _Float16 Tr[4096], Ti[4096];
  __shared__ __align__(16) float red[8];

  const int bx = blockIdx.x;
  const int b  = bx & (NB - 1);
  const int c  = bx >> 6;          // chunk id 0..NC-1
  const int t0 = c * CL;
  const int tid = threadIdx.x;
  const int lane = tid & 63, hi = lane >> 5, l31 = lane & 31, w = tid >> 6;
  const int grp = w >> 2, rblk = (w >> 1) & 1, pblk = w & 1;
  const int prow = 32 * rblk + l31;

  const float g = 1.0f / (1.0f + expf(-lam_p[0]));

  // U fragments (hi + lo*256)
  half8 Urh[4], Url[4], Uih[4], Uil[4];
  {
    const int row = 32 * pblk + l31;
    #pragma unroll
    for (int kq = 0; kq < 4; ++kq) {
      const int c0 = 16 * kq + 8 * hi;
      #pragma unroll
      for (int e = 0; e < 8; ++e) {
        const float ur = U_r[row * 64 + c0 + e];
        const float ui = U_i[row * 64 + c0 + e];
        _Float16 h;
        h = (_Float16)ur; Urh[kq][e] = h; Url[kq][e] = (_Float16)((ur - (float)h) * 256.0f);
        h = (_Float16)ui; Uih[kq][e] = h; Uil[kq][e] = (_Float16)((ui - (float)h) * 256.0f);
      }
    }
  }

  // x source for this thread's grp; per-step offset of its 4 float4 gathers
  const float* __restrict__ xsrc = grp ? data_i : data_r;
  const size_t xoff = (size_t)prow * 64 + 32 * pblk + 4 * hi;  // + 8*jj + t*NB*4096

  // ---- initial state ----
  float rv[16];
  if constexpr (PASS3) {
    if (c == 0) {
      #pragma unroll
      for (int j = 0; j < 16; ++j)
        rv[j] = (grp == 0 && prow == jcolf(j, pblk, hi)) ? (1.0f / 64.0f) : 0.0f;
    } else {
      const float* hs = out + ((size_t)((grp ? NT : 0) + t0 + 1) * NB + b) * 4096;
      #pragma unroll
      for (int j = 0; j < 16; ++j)
        rv[j] = hs[prow * 64 + jcolf(j, pblk, hi)];
    }
  } else {
    #pragma unroll
    for (int j = 0; j < 16; ++j) rv[j] = 0.0f;
  }
  // block max of |rv| -> entry normalization
  {
    float ml = 0.0f;
    #pragma unroll
    for (int j = 0; j < 16; ++j) ml = fmaxf(ml, fabsf(rv[j]));
    #pragma unroll
    for (int d = 32; d >= 1; d >>= 1) ml = fmaxf(ml, __shfl_xor(ml, d, 64));
    if (lane == 0) red[w] = ml;
  }

  // prefetch x_{t0} -> registers (consumption layout: [prow][32pblk+8jj+4hi..+3])
  float4_t px[4];
  {
    const float* xp = xsrc + (size_t)t0 * NB * 4096 + (size_t)b * 4096 + xoff;
    #pragma unroll
    for (int jj = 0; jj < 4; ++jj) px[jj] = *(const float4_t*)(xp + 8 * jj);
  }
  BARX();  // red published

  float Sig, alpha = 1.0f, alphainv = 1.0f;
  {
    float4_t r0 = *(const float4_t*)&red[0];
    float4_t r1 = *(const float4_t*)&red[4];
    float mm = fmaxf(fmaxf(fmaxf(r0[0], r0[1]), fmaxf(r0[2], r0[3])),
                     fmaxf(fmaxf(r1[0], r1[1]), fmaxf(r1[2], r1[3])));
    int E0 = 0;
    if (mm > 0.0f) frexpf(mm, &E0);
    const float sc = ldexpf(1.0f, -E0);
    #pragma unroll
    for (int j = 0; j < 16; ++j) rv[j] *= sc;   // normalize entry state
    Sig = ldexpf(1.0f, E0);                     // true h = Sig * rv
  }

  for (int s = 0; s < CL; ++s) {
    // ===== MIX (x from registers, f32; stale-1 alpha) =====
    {
      const float ga = g * alpha;
      const float kx = (1.0f - g) * alpha / Sig;
      _Float16* Vg = grp ? Vi : Vr;
      #pragma unroll
      for (int jj = 0; jj < 4; ++jj) {
        const int j0 = 32 * pblk + 8 * jj + 4 * hi;
        #pragma unroll
        for (int e = 0; e < 4; ++e) {
          const float vv = ga * rv[4 * jj + e] + kx * px[jj][e];
          Vg[eidx(j0 + e, prow)] = (_Float16)vv;   // V^T
        }
      }
      float m0[8];
      #pragma unroll
      for (int e = 0; e < 8; ++e) m0[e] = fmaxf(fabsf(rv[e]), fabsf(rv[e + 8]));
      #pragma unroll
      for (int e = 0; e < 4; ++e) m0[e] = fmaxf(m0[e], m0[e + 4]);
      float ml = fmaxf(fmaxf(m0[0], m0[1]), fmaxf(m0[2], m0[3]));
      #pragma unroll
      for (int d = 32; d >= 1; d >>= 1) ml = fmaxf(ml, __shfl_xor(ml, d, 64));
      if (lane == 0) red[w] = ml;
    }
    BARX();  // bar1: V, red published

    // ===== REGION2: prefetch x_{s+1}, out stores, alpha update, stage1 =====
    if (s + 1 < CL) {  // px dead after mix -> reload for next step (lands by next mix)
      const float* xp = xsrc + (size_t)(t0 + s + 1) * NB * 4096 + (size_t)b * 4096 + xoff;
      #pragma unroll
      for (int jj = 0; jj < 4; ++jj) px[jj] = *(const float4_t*)(xp + 8 * jj);
    }
    if constexpr (PASS3) {  // direct out store: true h^(s) = Sig_old * rv
      if (s > 0) {
        float* oR = out + ((size_t)(t0 + s - 1) * NB + b) * 4096
                        + (grp ? (size_t)NT * NB * 4096 : 0) + (size_t)(prow * 64);
        #pragma unroll
        for (int jj = 0; jj < 4; ++jj) {
          const int j0 = 32 * pblk + 8 * jj + 4 * hi;
          float4_t ov;
          #pragma unroll
          for (int e = 0; e < 4; ++e) ov[e] = Sig * rv[4 * jj + e];
          *(float4_t*)(oR + j0) = ov;
        }
      }
    }
    Sig *= alphainv;  // scale of the rv this step's matmuls produce
    {
      float4_t r0 = *(const float4_t*)&red[0];
      float4_t r1 = *(const float4_t*)&red[4];
      float mm = fmaxf(fmaxf(fmaxf(r0[0], r0[1]), fmaxf(r0[2], r0[3])),
                       fmaxf(fmaxf(r1[0], r1[1]), fmaxf(r1[2], r1[3])));
      int E = 0;
      if (mm > 0.0f) frexpf(mm, &E);
      alpha = ldexpf(1.0f, -E);   // for next mix (stale-1)
      alphainv = ldexpf(1.0f, E);
    }

    // stage1: t^T = V^T * U^T
    {
      half8 A0[4], A1[4];
      const int rrow = 32 * rblk + l31;
      #pragma unroll
      for (int kq = 0; kq < 4; ++kq) {
        const int cc = 16 * kq + 8 * hi;
        half8 avr = *(const half8*)&Vr[eidx(rrow, cc)];
        half8 avi = *(const half8*)&Vi[eidx(rrow, cc)];
        if (grp == 0) { A0[kq] = avr; A1[kq] = avi; }
        else          { A0[kq] = avi; A1[kq] = avr; }
      }
      floatx16 a1h, a1l, a2h, a2l;
      #pragma unroll
      for (int j = 0; j < 16; ++j) { a1h[j] = 0; a1l[j] = 0; a2h[j] = 0; a2l[j] = 0; }
      #pragma unroll
      for (int kq = 0; kq < 4; ++kq) {
        a1h = __builtin_amdgcn_mfma_f32_32x32x16_f16(A0[kq], Urh[kq], a1h, 0, 0, 0);
        a2h = __builtin_amdgcn_mfma_f32_32x32x16_f16(A1[kq], Uih[kq], a2h, 0, 0, 0);
        a1l = __builtin_amdgcn_mfma_f32_32x32x16_f16(A0[kq], Url[kq], a1l, 0, 0, 0);
        a2l = __builtin_amdgcn_mfma_f32_32x32x16_f16(A1[kq], Uil[kq], a2l, 0, 0, 0);
      }
      const float s1 = grp ? 1.0f : -1.0f;
      _Float16* Tg = grp ? Ti : Tr;
      const int tp = 32 * pblk + l31;
      #pragma unroll
      for (int jj = 0; jj < 4; ++jj) {
        const int rr0 = 32 * rblk + 8 * jj + 4 * hi;
        half4_t tv;
        #pragma unroll
        for (int e = 0; e < 4; ++e) {
          const int j = 4 * jj + e;
          tv[e] = (_Float16)((a1h[j] + s1 * a2h[j]) + (a1l[j] + s1 * a2l[j]) * 0.00390625f);
        }
        *(half4_t*)&Tg[eidx(tp, rr0)] = tv;
      }
    }
    BARX();  // bar2: T published

    // stage2: h'^T = U * t^T -> rv
    {
      half8 B0[4], B1[4];
      const int p2 = 32 * rblk + l31;
      #pragma unroll
      for (int kq = 0; kq < 4; ++kq) {
        const int cc = 16 * kq + 8 * hi;
        half8 btr = *(const half8*)&Tr[eidx(p2, cc)];
        half8 bti = *(const half8*)&Ti[eidx(p2, cc)];
        if (grp == 0) { B0[kq] = btr; B1[kq] = bti; }
        else          { B0[kq] = bti; B1[kq] = btr; }
      }
      floatx16 c1h, c1l, c2h, c2l;
      #pragma unroll
      for (int j = 0; j < 16; ++j) { c1h[j] = 0; c1l[j] = 0; c2h[j] = 0; c2l[j] = 0; }
      #pragma unroll
      for (int kq = 0; kq < 4; ++kq) {
        c1h = __builtin_amdgcn_mfma_f32_32x32x16_f16(Urh[kq], B0[kq], c1h, 0, 0, 0);
        c2h = __builtin_amdgcn_mfma_f32_32x32x16_f16(Uih[kq], B1[kq], c2h, 0, 0, 0);
        c1l = __builtin_amdgcn_mfma_f32_32x32x16_f16(Url[kq], B0[kq], c1l, 0, 0, 0);
        c2l = __builtin_amdgcn_mfma_f32_32x32x16_f16(Uil[kq], B1[kq], c2l, 0, 0, 0);
      }
      const float s2 = grp ? -1.0f : 1.0f;
      #pragma unroll
      for (int j = 0; j < 16; ++j)
        rv[j] = (c1h[j] + s2 * c2h[j]) + (c1l[j] + s2 * c2l[j]) * 0.00390625f;
    }
  }

  // ---- epilogue: direct store of final state (true h = Sig * rv) ----
  {
    const int trow = PASS3 ? (t0 + CL - 1) : t0;
    float* eR = out + ((size_t)trow * NB + b) * 4096
                    + (grp ? (size_t)NT * NB * 4096 : 0) + (size_t)(prow * 64);
    #pragma unroll
    for (int jj = 0; jj < 4; ++jj) {
      const int j0 = 32 * pblk + 8 * jj + 4 * hi;
      float4_t ov;
      #pragma unroll
      for (int e = 0; e < 4; ++e) ov[e] = Sig * rv[4 * jj + e];
      *(float4_t*)(eR + j0) = ov;
    }
  }
}

// ---------------- K2: W = U^CL (NSQ squarings) + NC-1 sequential chunk combines ----
__global__ __launch_bounds__(512, 1)
void qrnn_combine(const float* __restrict__ U_r, const float* __restrict__ U_i,
                  const float* __restrict__ lam_p, float* __restrict__ out) {
  __shared__ float Ga_r[64 * 68], Ga_i[64 * 68], Gb_r[64 * 68], Gb_i[64 * 68];
  __shared__ __align__(16) _Float16 Vr[4096], Vi[4096], Tr[4096], Ti[4096];
  __shared__ float red[8];

  const int b = blockIdx.x;
  const int tid = threadIdx.x;
  const int lane = tid & 63, hi = lane >> 5, l31 = lane & 31, w = tid >> 6;
  const int grp = w >> 2, rblk = (w >> 1) & 1, pblk = w & 1;
  const int prow = 32 * rblk + l31;

  const float g = 1.0f / (1.0f + expf(-lam_p[0]));
  float gCL = g;
  #pragma unroll
  for (int i = 0; i < NSQ; ++i) gCL *= gCL;   // g^(2^NSQ) = g^CL

  // load U -> Ga
  const int qr = tid >> 3, qc = (tid & 7) * 8;
  {
    *(float4_t*)&Ga_r[qr * 68 + qc]     = *(const float4_t*)(U_r + qr * 64 + qc);
    *(float4_t*)&Ga_r[qr * 68 + qc + 4] = *(const float4_t*)(U_r + qr * 64 + qc + 4);
    *(float4_t*)&Ga_i[qr * 68 + qc]     = *(const float4_t*)(U_i + qr * 64 + qc);
    *(float4_t*)&Ga_i[qr * 68 + qc + 4] = *(const float4_t*)(U_i + qr * 64 + qc + 4);
  }
  __syncthreads();

  // NSQ squarings (alternating Ga<->Gb); result in Gb for odd NSQ
  #pragma unroll
  for (int it = 0; it < NSQ; ++it) {
    const float* sr = (it & 1) ? Gb_r : Ga_r;
    const float* si = (it & 1) ? Gb_i : Ga_i;
    float* dr = (it & 1) ? Ga_r : Gb_r;
    float* di = (it & 1) ? Ga_i : Gb_i;
    float cr[8], ci[8];
    #pragma unroll
    for (int e = 0; e < 8; ++e) { cr[e] = 0.0f; ci[e] = 0.0f; }
    for (int k = 0; k < 64; ++k) {
      const float ar = sr[qr * 68 + k];
      const float ai = si[qr * 68 + k];
      float4_t br0 = *(const float4_t*)&sr[k * 68 + qc];
      float4_t br1 = *(const float4_t*)&sr[k * 68 + qc + 4];
      float4_t bi0 = *(const float4_t*)&si[k * 68 + qc];
      float4_t bi1 = *(const float4_t*)&si[k * 68 + qc + 4];
      #pragma unroll
      for (int e = 0; e < 4; ++e) {
        cr[e]     += ar * br0[e] - ai * bi0[e];
        ci[e]     += ar * bi0[e] + ai * br0[e];
        cr[4 + e] += ar * br1[e] - ai * bi1[e];
        ci[4 + e] += ar * bi1[e] + ai * br1[e];
      }
    }
    float4_t s0, s1, s2, s3;
    #pragma unroll
    for (int e = 0; e < 4; ++e) { s0[e] = cr[e]; s1[e] = cr[4 + e]; s2[e] = ci[e]; s3[e] = ci[4 + e]; }
    *(float4_t*)&dr[qr * 68 + qc] = s0;  *(float4_t*)&dr[qr * 68 + qc + 4] = s1;
    *(float4_t*)&di[qr * 68 + qc] = s2;  *(float4_t*)&di[qr * 68 + qc + 4] = s3;
    __syncthreads();
  }
  const float* Wr_ = (NSQ & 1) ? Gb_r : Ga_r;
  const float* Wi_ = (NSQ & 1) ? Gb_i : Ga_i;

  // extract W frags (hi + lo*256)
  half8 Wrh[4], Wrl[4], Wih[4], Wil[4];
  {
    const int row = 32 * pblk + l31;
    #pragma unroll
    for (int kq = 0; kq < 4; ++kq) {
      const int c0 = 16 * kq + 8 * hi;
      #pragma unroll
      for (int e = 0; e < 8; ++e) {
        const float wr = Wr_[row * 68 + c0 + e];
        const float wi = Wi_[row * 68 + c0 + e];
        _Float16 h;
        h = (_Float16)wr; Wrh[kq][e] = h; Wrl[kq][e] = (_Float16)((wr - (float)h) * 256.0f);
        h = (_Float16)wi; Wih[kq][e] = h; Wil[kq][e] = (_Float16)((wi - (float)h) * 256.0f);
      }
    }
  }

  // H = h0
  float rv[16];
  #pragma unroll
  for (int j = 0; j < 16; ++j)
    rv[j] = (grp == 0 && prow == jcolf(j, pblk, hi)) ? (1.0f / 64.0f) : 0.0f;

  for (int c = 0; c < NC - 1; ++c) {
    float pv[16];
    {
      const float* ps = out + ((size_t)((grp ? NT : 0) + c * CL) * NB + b) * 4096;
      #pragma unroll
      for (int j = 0; j < 16; ++j) pv[j] = ps[prow * 64 + jcolf(j, pblk, hi)];
    }
    float ml = 0.0f;
    #pragma unroll
    for (int j = 0; j < 16; ++j) ml = fmaxf(ml, fabsf(rv[j]));
    #pragma unroll
    for (int d = 32; d >= 1; d >>= 1) ml = fmaxf(ml, __shfl_xor(ml, d, 64));
    if (lane == 0) red[w] = ml;
    __syncthreads();
    float mm = red[0];
    #pragma unroll
    for (int i = 1; i < 8; ++i) mm = fmaxf(mm, red[i]);
    int E = 0;
    if (mm > 0.0f) frexpf(mm, &E);
    const float al = ldexpf(1.0f, -E);
    const float fE = gCL * ldexpf(1.0f, E);

    {
      _Float16* Vg = grp ? Vi : Vr;
      #pragma unroll
      for (int j = 0; j < 16; ++j)
        Vg[eidx(jcolf(j, pblk, hi), prow)] = (_Float16)(al * rv[j]);
    }
    __syncthreads();

    {
      half8 A0[4], A1[4];
      const int rrow = 32 * rblk + l31;
      #pragma unroll
      for (int kq = 0; kq < 4; ++kq) {
        const int cc = 16 * kq + 8 * hi;
        half8 avr = *(const half8*)&Vr[eidx(rrow, cc)];
        half8 avi = *(const half8*)&Vi[eidx(rrow, cc)];
        if (grp == 0) { A0[kq] = avr; A1[kq] = avi; }
        else          { A0[kq] = avi; A1[kq] = avr; }
      }
      floatx16 a1h, a1l, a2h, a2l;
      #pragma unroll
      for (int j = 0; j < 16; ++j) { a1h[j] = 0; a1l[j] = 0; a2h[j] = 0; a2l[j] = 0; }
      #pragma unroll
      for (int kq = 0; kq < 4; ++kq) {
        a1h = __builtin_amdgcn_mfma_f32_32x32x16_f16(A0[kq], Wrh[kq], a1h, 0, 0, 0);
        a2h = __builtin_amdgcn_mfma_f32_32x32x16_f16(A1[kq], Wih[kq], a2h, 0, 0, 0);
        a1l = __builtin_amdgcn_mfma_f32_32x32x16_f16(A0[kq], Wrl[kq], a1l, 0, 0, 0);
        a2l = __builtin_amdgcn_mfma_f32_32x32x16_f16(A1[kq], Wil[kq], a2l, 0, 0, 0);
      }
      const float s1 = grp ? 1.0f : -1.0f;
      _Float16* Tg = grp ? Ti : Tr;
      const int tp = 32 * pblk + l31;
      #pragma unroll
      for (int jj = 0; jj < 4; ++jj) {
        const int rr0 = 32 * rblk + 8 * jj + 4 * hi;
        half4_t tv;
        #pragma unroll
        for (int e = 0; e < 4; ++e) {
          const int j = 4 * jj + e;
          tv[e] = (_Float16)((a1h[j] + s1 * a2h[j]) + (a1l[j] + s1 * a2l[j]) * 0.00390625f);
        }
        *(half4_t*)&Tg[eidx(tp, rr0)] = tv;
      }
    }
    __syncthreads();

    {
      half8 B0[4], B1[4];
      const int p2 = 32 * rblk + l31;
      #pragma unroll
      for (int kq = 0; kq < 4; ++kq) {
        const int cc = 16 * kq + 8 * hi;
        half8 btr = *(const half8*)&Tr[eidx(p2, cc)];
        half8 bti = *(const half8*)&Ti[eidx(p2, cc)];
        if (grp == 0) { B0[kq] = btr; B1[kq] = bti; }
        else          { B0[kq] = bti; B1[kq] = btr; }
      }
      floatx16 c1h, c1l, c2h, c2l;
      #pragma unroll
      for (int j = 0; j < 16; ++j) { c1h[j] = 0; c1l[j] = 0; c2h[j] = 0; c2l[j] = 0; }
      #pragma unroll
      for (int kq = 0; kq < 4; ++kq) {
        c1h = __builtin_amdgcn_mfma_f32_32x32x16_f16(Wrh[kq], B0[kq], c1h, 0, 0, 0);
        c2h = __builtin_amdgcn_mfma_f32_32x32x16_f16(Wih[kq], B1[kq], c2h, 0, 0, 0);
        c1l = __builtin_amdgcn_mfma_f32_32x32x16_f16(Wrl[kq], B0[kq], c1l, 0, 0, 0);
        c2l = __builtin_amdgcn_mfma_f32_32x32x16_f16(Wil[kq], B1[kq], c2l, 0, 0, 0);
      }
      const float s2 = grp ? -1.0f : 1.0f;
      #pragma unroll
      for (int j = 0; j < 16; ++j) {
        const float rvS = (c1h[j] + s2 * c2h[j]) + (c1l[j] + s2 * c2l[j]) * 0.00390625f;
        rv[j] = fE * rvS + pv[j];
      }
    }
    {
      float* hs = out + ((size_t)((grp ? NT : 0) + (c + 1) * CL + 1) * NB + b) * 4096;
      #pragma unroll
      for (int j = 0; j < 16; ++j) hs[prow * 64 + jcolf(j, pblk, hi)] = rv[j];
    }
    __syncthreads();
  }
}

extern "C" void kernel_launch(void* const* d_in, const int* in_sizes, int n_in,
                              void* d_out, int out_size, void* d_ws, size_t ws_size,
                              hipStream_t stream) {
  (void)in_sizes; (void)n_in; (void)out_size; (void)d_ws; (void)ws_size;
  const float* dr = (const float*)d_in[0];
  const float* di = (const float*)d_in[1];
  const float* ur = (const float*)d_in[2];
  const float* ui = (const float*)d_in[3];
  const float* lm = (const float*)d_in[4];
  float* o = (float*)d_out;
  qrnn_scan<false><<<dim3(NB * NC), dim3(512), 0, stream>>>(dr, di, ur, ui, lm, o);
  qrnn_combine<<<dim3(NB), dim3(512), 0, stream>>>(ur, ui, lm, o);
  qrnn_scan<true><<<dim3(NB * NC), dim3(512), 0, stream>>>(dr, di, ur, ui, lm, o);
}

// Round 9
// 515.169 us; speedup vs baseline: 8.0973x; 8.0973x over previous
//
#include <hip/hip_runtime.h>
#include <math.h>

typedef _Float16 half8 __attribute__((ext_vector_type(8)));
typedef _Float16 half4_t __attribute__((ext_vector_type(4)));
typedef float floatx16 __attribute__((ext_vector_type(16)));
typedef float float4_t __attribute__((ext_vector_type(4)));

#define NT 128
#define NB 64
#define NC 8
#define CL 16

// element index with 8-f16 (16B) unit XOR swizzle inside a 64-f16 (128B) row
__device__ __forceinline__ int eidx(int row, int col) {
  return row * 64 + ((((col >> 3) ^ row) & 7) << 3) + (col & 7);
}
__device__ __forceinline__ int jcolf(int j, int pblk, int hi) {
  return 32 * pblk + (j & 3) + 8 * (j >> 2) + 4 * hi;
}

// LDS-only barrier (globals never carry intra-kernel cross-wave data here)
#define BARX() do {                                        \
  asm volatile("s_waitcnt lgkmcnt(0)" ::: "memory");       \
  __builtin_amdgcn_s_barrier();                            \
  __builtin_amdgcn_sched_barrier(0);                       \
} while (0)
#define WAITONLY() do {                                    \
  asm volatile("s_waitcnt lgkmcnt(0)" ::: "memory");       \
  __builtin_amdgcn_sched_barrier(0);                       \
} while (0)

// ================= REAL chunk scan (R7, verified 169us/pass) =================
template<bool PASS3>
__global__ __launch_bounds__(512, 2)
void qrnn_scan(const float* __restrict__ data_r, const float* __restrict__ data_i,
               const float* __restrict__ U_r, const float* __restrict__ U_i,
               const float* __restrict__ lam_p, float* __restrict__ out) {
  __shared__ __align__(16) _Float16 Vr[4096], Vi[4096];
  __shared__ __align__(16) _Float16 Tr[4096], Ti[4096];
  __shared__ __align__(16) _Float16 Xr[2][4096], Xi[2][4096];
  __shared__ __align__(16) float red[8];

  const int bx = blockIdx.x;
  const int b  = bx & (NB - 1);
  const int c  = bx >> 6;
  const int t0 = c * CL;
  const int tid = threadIdx.x;
  const int lane = tid & 63, hi = lane >> 5, l31 = lane & 31, w = tid >> 6;
  const int grp = w >> 2, rblk = (w >> 1) & 1, pblk = w & 1;
  const int prow = 32 * rblk + l31;

  const float g = 1.0f / (1.0f + expf(-lam_p[0]));

  half8 Urh[4], Url[4], Uih[4], Uil[4];
  {
    const int row = 32 * pblk + l31;
    #pragma unroll
    for (int kq = 0; kq < 4; ++kq) {
      const int c0 = 16 * kq + 8 * hi;
      #pragma unroll
      for (int e = 0; e < 8; ++e) {
        const float ur = U_r[row * 64 + c0 + e];
        const float ui = U_i[row * 64 + c0 + e];
        _Float16 h;
        h = (_Float16)ur; Urh[kq][e] = h; Url[kq][e] = (_Float16)((ur - (float)h) * 256.0f);
        h = (_Float16)ui; Uih[kq][e] = h; Uil[kq][e] = (_Float16)((ui - (float)h) * 256.0f);
      }
    }
  }

  float rv[16];
  if constexpr (PASS3) {
    if (c == 0) {
      #pragma unroll
      for (int j = 0; j < 16; ++j)
        rv[j] = (grp == 0 && prow == jcolf(j, pblk, hi)) ? (1.0f / 64.0f) : 0.0f;
    } else {
      const float* hs = out + ((size_t)((grp ? NT : 0) + t0 + 1) * NB + b) * 4096;
      #pragma unroll
      for (int j = 0; j < 16; ++j)
        rv[j] = hs[prow * 64 + jcolf(j, pblk, hi)];
    }
  } else {
    #pragma unroll
    for (int j = 0; j < 16; ++j) rv[j] = 0.0f;
  }
  {
    float ml = 0.0f;
    #pragma unroll
    for (int j = 0; j < 16; ++j) ml = fmaxf(ml, fabsf(rv[j]));
    #pragma unroll
    for (int d = 32; d >= 1; d >>= 1) ml = fmaxf(ml, __shfl_xor(ml, d, 64));
    if (lane == 0) red[w] = ml;
  }

  const int dq = tid >> 3, dr0 = (tid & 7) * 8;
  {
    const size_t xb = ((size_t)t0 * NB + b) * 4096 + (size_t)(dq * 64 + dr0);
    float4_t a0 = *(const float4_t*)(data_r + xb);
    float4_t a1 = *(const float4_t*)(data_r + xb + 4);
    float4_t c0 = *(const float4_t*)(data_i + xb);
    float4_t c1 = *(const float4_t*)(data_i + xb + 4);
    half8 hx, hy;
    #pragma unroll
    for (int e = 0; e < 4; ++e) {
      hx[e] = (_Float16)a0[e]; hx[4 + e] = (_Float16)a1[e];
      hy[e] = (_Float16)c0[e]; hy[4 + e] = (_Float16)c1[e];
    }
    *(half8*)&Xr[0][eidx(dq, dr0)] = hx;
    *(half8*)&Xi[0][eidx(dq, dr0)] = hy;
  }
  float4_t pa0, pa1, pb0, pb1;
  {
    const size_t xb = ((size_t)(t0 + 1) * NB + b) * 4096 + (size_t)(dq * 64 + dr0);
    pa0 = *(const float4_t*)(data_r + xb);
    pa1 = *(const float4_t*)(data_r + xb + 4);
    pb0 = *(const float4_t*)(data_i + xb);
    pb1 = *(const float4_t*)(data_i + xb + 4);
  }
  BARX();

  float Sig, alpha = 1.0f, alphainv = 1.0f;
  {
    float4_t r0 = *(const float4_t*)&red[0];
    float4_t r1 = *(const float4_t*)&red[4];
    float mm = fmaxf(fmaxf(fmaxf(r0[0], r0[1]), fmaxf(r0[2], r0[3])),
                     fmaxf(fmaxf(r1[0], r1[1]), fmaxf(r1[2], r1[3])));
    int E0 = 0;
    if (mm > 0.0f) frexpf(mm, &E0);
    const float sc = ldexpf(1.0f, -E0);
    #pragma unroll
    for (int j = 0; j < 16; ++j) rv[j] *= sc;
    Sig = ldexpf(1.0f, E0);
  }

  for (int s = 0; s < CL; ++s) {
    {
      const float ga = g * alpha;
      const float kx = (1.0f - g) * alpha / Sig;
      const _Float16* Xg = grp ? Xi[s & 1] : Xr[s & 1];
      _Float16* Vg = grp ? Vi : Vr;
      #pragma unroll
      for (int jj = 0; jj < 4; ++jj) {
        const int j0 = 32 * pblk + 8 * jj + 4 * hi;
        half4_t xv = *(const half4_t*)&Xg[eidx(prow, j0)];
        #pragma unroll
        for (int e = 0; e < 4; ++e) {
          const float r = rv[4 * jj + e];
          const float vv = ga * r + kx * (float)xv[e];
          Vg[eidx(j0 + e, prow)] = (_Float16)vv;
        }
      }
      float m0[8];
      #pragma unroll
      for (int e = 0; e < 8; ++e) m0[e] = fmaxf(fabsf(rv[e]), fabsf(rv[e + 8]));
      #pragma unroll
      for (int e = 0; e < 4; ++e) m0[e] = fmaxf(m0[e], m0[e + 4]);
      float ml = fmaxf(fmaxf(m0[0], m0[1]), fmaxf(m0[2], m0[3]));
      #pragma unroll
      for (int d = 32; d >= 1; d >>= 1) ml = fmaxf(ml, __shfl_xor(ml, d, 64));
      if (lane == 0) red[w] = ml;
    }
    BARX();

    if (s + 1 < CL) {
      half8 hx, hy;
      #pragma unroll
      for (int e = 0; e < 4; ++e) {
        hx[e] = (_Float16)pa0[e]; hx[4 + e] = (_Float16)pa1[e];
        hy[e] = (_Float16)pb0[e]; hy[4 + e] = (_Float16)pb1[e];
      }
      *(half8*)&Xr[(s + 1) & 1][eidx(dq, dr0)] = hx;
      *(half8*)&Xi[(s + 1) & 1][eidx(dq, dr0)] = hy;
    }
    if (s + 2 < CL) {
      const size_t xb = ((size_t)(t0 + s + 2) * NB + b) * 4096 + (size_t)(dq * 64 + dr0);
      pa0 = *(const float4_t*)(data_r + xb);
      pa1 = *(const float4_t*)(data_r + xb + 4);
      pb0 = *(const float4_t*)(data_i + xb);
      pb1 = *(const float4_t*)(data_i + xb + 4);
    }
    if constexpr (PASS3) {
      if (s > 0) {
        float* oR = out + ((size_t)(t0 + s - 1) * NB + b) * 4096
                        + (grp ? (size_t)NT * NB * 4096 : 0) + (size_t)(prow * 64);
        #pragma unroll
        for (int jj = 0; jj < 4; ++jj) {
          const int j0 = 32 * pblk + 8 * jj + 4 * hi;
          float4_t ov;
          #pragma unroll
          for (int e = 0; e < 4; ++e) ov[e] = Sig * rv[4 * jj + e];
          *(float4_t*)(oR + j0) = ov;
        }
      }
    }
    Sig *= alphainv;
    {
      float4_t r0 = *(const float4_t*)&red[0];
      float4_t r1 = *(const float4_t*)&red[4];
      float mm = fmaxf(fmaxf(fmaxf(r0[0], r0[1]), fmaxf(r0[2], r0[3])),
                       fmaxf(fmaxf(r1[0], r1[1]), fmaxf(r1[2], r1[3])));
      int E = 0;
      if (mm > 0.0f) frexpf(mm, &E);
      alpha = ldexpf(1.0f, -E);
      alphainv = ldexpf(1.0f, E);
    }

    {
      half8 A0[4], A1[4];
      const int rrow = 32 * rblk + l31;
      #pragma unroll
      for (int kq = 0; kq < 4; ++kq) {
        const int cc = 16 * kq + 8 * hi;
        half8 avr = *(const half8*)&Vr[eidx(rrow, cc)];
        half8 avi = *(const half8*)&Vi[eidx(rrow, cc)];
        if (grp == 0) { A0[kq] = avr; A1[kq] = avi; }
        else          { A0[kq] = avi; A1[kq] = avr; }
      }
      floatx16 a1h, a1l, a2h, a2l;
      #pragma unroll
      for (int j = 0; j < 16; ++j) { a1h[j] = 0; a1l[j] = 0; a2h[j] = 0; a2l[j] = 0; }
      #pragma unroll
      for (int kq = 0; kq < 4; ++kq) {
        a1h = __builtin_amdgcn_mfma_f32_32x32x16_f16(A0[kq], Urh[kq], a1h, 0, 0, 0);
        a2h = __builtin_amdgcn_mfma_f32_32x32x16_f16(A1[kq], Uih[kq], a2h, 0, 0, 0);
        a1l = __builtin_amdgcn_mfma_f32_32x32x16_f16(A0[kq], Url[kq], a1l, 0, 0, 0);
        a2l = __builtin_amdgcn_mfma_f32_32x32x16_f16(A1[kq], Uil[kq], a2l, 0, 0, 0);
      }
      const float s1 = grp ? 1.0f : -1.0f;
      _Float16* Tg = grp ? Ti : Tr;
      const int tp = 32 * pblk + l31;
      #pragma unroll
      for (int jj = 0; jj < 4; ++jj) {
        const int rr0 = 32 * rblk + 8 * jj + 4 * hi;
        half4_t tv;
        #pragma unroll
        for (int e = 0; e < 4; ++e) {
          const int j = 4 * jj + e;
          tv[e] = (_Float16)((a1h[j] + s1 * a2h[j]) + (a1l[j] + s1 * a2l[j]) * 0.00390625f);
        }
        *(half4_t*)&Tg[eidx(tp, rr0)] = tv;
      }
    }
    BARX();

    {
      half8 B0[4], B1[4];
      const int p2 = 32 * rblk + l31;
      #pragma unroll
      for (int kq = 0; kq < 4; ++kq) {
        const int cc = 16 * kq + 8 * hi;
        half8 btr = *(const half8*)&Tr[eidx(p2, cc)];
        half8 bti = *(const half8*)&Ti[eidx(p2, cc)];
        if (grp == 0) { B0[kq] = btr; B1[kq] = bti; }
        else          { B0[kq] = bti; B1[kq] = btr; }
      }
      floatx16 c1h, c1l, c2h, c2l;
      #pragma unroll
      for (int j = 0; j < 16; ++j) { c1h[j] = 0; c1l[j] = 0; c2h[j] = 0; c2l[j] = 0; }
      #pragma unroll
      for (int kq = 0; kq < 4; ++kq) {
        c1h = __builtin_amdgcn_mfma_f32_32x32x16_f16(Urh[kq], B0[kq], c1h, 0, 0, 0);
        c2h = __builtin_amdgcn_mfma_f32_32x32x16_f16(Uih[kq], B1[kq], c2h, 0, 0, 0);
        c1l = __builtin_amdgcn_mfma_f32_32x32x16_f16(Url[kq], B0[kq], c1l, 0, 0, 0);
        c2l = __builtin_amdgcn_mfma_f32_32x32x16_f16(Uil[kq], B1[kq], c2l, 0, 0, 0);
      }
      const float s2 = grp ? -1.0f : 1.0f;
      #pragma unroll
      for (int j = 0; j < 16; ++j)
        rv[j] = (c1h[j] + s2 * c2h[j]) + (c1l[j] + s2 * c2l[j]) * 0.00390625f;
    }
  }

  {
    const int trow = PASS3 ? (t0 + CL - 1) : t0;
    float* eR = out + ((size_t)trow * NB + b) * 4096
                    + (grp ? (size_t)NT * NB * 4096 : 0) + (size_t)(prow * 64);
    #pragma unroll
    for (int jj = 0; jj < 4; ++jj) {
      const int j0 = 32 * pblk + 8 * jj + 4 * hi;
      float4_t ov;
      #pragma unroll
      for (int e = 0; e < 4; ++e) ov[e] = Sig * rv[4 * jj + e];
      *(float4_t*)(eR + j0) = ov;
    }
  }
}

// ================= ABLATION clone of PASS1 (store-free; timing via rocprof) ====
// ABL=1: MFMAs removed.  ABL=2: V/T ds_reads removed.  ABL=4: s_barrier removed.
template<int ABL>
__global__ __launch_bounds__(512, 2)
void qrnn_abl(const float* __restrict__ data_r, const float* __restrict__ data_i,
              const float* __restrict__ U_r, const float* __restrict__ U_i,
              const float* __restrict__ lam_p, float* __restrict__ out) {
  __shared__ __align__(16) _Float16 Vr[4096], Vi[4096];
  __shared__ __align__(16) _Float16 Tr[4096], Ti[4096];
  __shared__ __align__(16) _Float16 Xr[2][4096], Xi[2][4096];
  __shared__ __align__(16) float red[8];

  const int bx = blockIdx.x;
  const int b  = bx & (NB - 1);
  const int c  = bx >> 6;
  const int t0 = c * CL;
  const int tid = threadIdx.x;
  const int lane = tid & 63, hi = lane >> 5, l31 = lane & 31, w = tid >> 6;
  const int grp = w >> 2, rblk = (w >> 1) & 1, pblk = w & 1;
  const int prow = 32 * rblk + l31;

  const float g = 1.0f / (1.0f + expf(-lam_p[0]));

  half8 Urh[4], Url[4], Uih[4], Uil[4];
  {
    const int row = 32 * pblk + l31;
    #pragma unroll
    for (int kq = 0; kq < 4; ++kq) {
      const int c0 = 16 * kq + 8 * hi;
      #pragma unroll
      for (int e = 0; e < 8; ++e) {
        const float ur = U_r[row * 64 + c0 + e];
        const float ui = U_i[row * 64 + c0 + e];
        _Float16 h;
        h = (_Float16)ur; Urh[kq][e] = h; Url[kq][e] = (_Float16)((ur - (float)h) * 256.0f);
        h = (_Float16)ui; Uih[kq][e] = h; Uil[kq][e] = (_Float16)((ui - (float)h) * 256.0f);
      }
    }
  }

  float rv[16];
  #pragma unroll
  for (int j = 0; j < 16; ++j) rv[j] = 0.0f;
  {
    float ml = 0.0f;
    #pragma unroll
    for (int j = 0; j < 16; ++j) ml = fmaxf(ml, fabsf(rv[j]));
    #pragma unroll
    for (int d = 32; d >= 1; d >>= 1) ml = fmaxf(ml, __shfl_xor(ml, d, 64));
    if (lane == 0) red[w] = ml;
  }

  const int dq = tid >> 3, dr0 = (tid & 7) * 8;
  {
    const size_t xb = ((size_t)t0 * NB + b) * 4096 + (size_t)(dq * 64 + dr0);
    float4_t a0 = *(const float4_t*)(data_r + xb);
    float4_t a1 = *(const float4_t*)(data_r + xb + 4);
    float4_t c0 = *(const float4_t*)(data_i + xb);
    float4_t c1 = *(const float4_t*)(data_i + xb + 4);
    half8 hx, hy;
    #pragma unroll
    for (int e = 0; e < 4; ++e) {
      hx[e] = (_Float16)a0[e]; hx[4 + e] = (_Float16)a1[e];
      hy[e] = (_Float16)c0[e]; hy[4 + e] = (_Float16)c1[e];
    }
    *(half8*)&Xr[0][eidx(dq, dr0)] = hx;
    *(half8*)&Xi[0][eidx(dq, dr0)] = hy;
  }
  float4_t pa0, pa1, pb0, pb1;
  {
    const size_t xb = ((size_t)(t0 + 1) * NB + b) * 4096 + (size_t)(dq * 64 + dr0);
    pa0 = *(const float4_t*)(data_r + xb);
    pa1 = *(const float4_t*)(data_r + xb + 4);
    pb0 = *(const float4_t*)(data_i + xb);
    pb1 = *(const float4_t*)(data_i + xb + 4);
  }
  if constexpr (ABL == 4) WAITONLY(); else BARX();

  float Sig = 1.0f, alpha = 1.0f, alphainv = 1.0f;

  for (int s = 0; s < CL; ++s) {
    // MIX (kept in all variants)
    {
      const float ga = g * alpha;
      const float kx = (1.0f - g) * alpha / Sig;
      const _Float16* Xg = grp ? Xi[s & 1] : Xr[s & 1];
      _Float16* Vg = grp ? Vi : Vr;
      #pragma unroll
      for (int jj = 0; jj < 4; ++jj) {
        const int j0 = 32 * pblk + 8 * jj + 4 * hi;
        half4_t xv = *(const half4_t*)&Xg[eidx(prow, j0)];
        #pragma unroll
        for (int e = 0; e < 4; ++e) {
          const float r = rv[4 * jj + e];
          const float vv = ga * r + kx * (float)xv[e];
          Vg[eidx(j0 + e, prow)] = (_Float16)vv;
        }
      }
      float m0[8];
      #pragma unroll
      for (int e = 0; e < 8; ++e) m0[e] = fmaxf(fabsf(rv[e]), fabsf(rv[e + 8]));
      #pragma unroll
      for (int e = 0; e < 4; ++e) m0[e] = fmaxf(m0[e], m0[e + 4]);
      float ml = fmaxf(fmaxf(m0[0], m0[1]), fmaxf(m0[2], m0[3]));
      #pragma unroll
      for (int d = 32; d >= 1; d >>= 1) ml = fmaxf(ml, __shfl_xor(ml, d, 64));
      if (lane == 0) red[w] = ml;
    }
    if constexpr (ABL == 4) WAITONLY(); else BARX();

    if (s + 1 < CL) {
      half8 hx, hy;
      #pragma unroll
      for (int e = 0; e < 4; ++e) {
        hx[e] = (_Float16)pa0[e]; hx[4 + e] = (_Float16)pa1[e];
        hy[e] = (_Float16)pb0[e]; hy[4 + e] = (_Float16)pb1[e];
      }
      *(half8*)&Xr[(s + 1) & 1][eidx(dq, dr0)] = hx;
      *(half8*)&Xi[(s + 1) & 1][eidx(dq, dr0)] = hy;
    }
    if (s + 2 < CL) {
      const size_t xb = ((size_t)(t0 + s + 2) * NB + b) * 4096 + (size_t)(dq * 64 + dr0);
      pa0 = *(const float4_t*)(data_r + xb);
      pa1 = *(const float4_t*)(data_r + xb + 4);
      pb0 = *(const float4_t*)(data_i + xb);
      pb1 = *(const float4_t*)(data_i + xb + 4);
    }
    Sig *= alphainv;
    {
      float4_t r0 = *(const float4_t*)&red[0];
      float4_t r1 = *(const float4_t*)&red[4];
      float mm = fmaxf(fmaxf(fmaxf(r0[0], r0[1]), fmaxf(r0[2], r0[3])),
                       fmaxf(fmaxf(r1[0], r1[1]), fmaxf(r1[2], r1[3])));
      int E = 0;
      if (mm > 0.0f) frexpf(mm, &E);
      alpha = ldexpf(1.0f, -E);
      alphainv = ldexpf(1.0f, E);
    }

    // stage1
    {
      half8 A0[4], A1[4];
      const int rrow = 32 * rblk + l31;
      if constexpr (ABL == 2) {
        #pragma unroll
        for (int kq = 0; kq < 4; ++kq) {
          const _Float16 hs0 = (_Float16)rv[kq];
          const _Float16 hs1 = (_Float16)rv[kq + 4];
          #pragma unroll
          for (int e = 0; e < 8; ++e) { A0[kq][e] = hs0; A1[kq][e] = hs1; }
        }
      } else {
        #pragma unroll
        for (int kq = 0; kq < 4; ++kq) {
          const int cc = 16 * kq + 8 * hi;
          half8 avr = *(const half8*)&Vr[eidx(rrow, cc)];
          half8 avi = *(const half8*)&Vi[eidx(rrow, cc)];
          if (grp == 0) { A0[kq] = avr; A1[kq] = avi; }
          else          { A0[kq] = avi; A1[kq] = avr; }
        }
      }
      _Float16* Tg = grp ? Ti : Tr;
      const int tp = 32 * pblk + l31;
      if constexpr (ABL == 1) {
        #pragma unroll
        for (int jj = 0; jj < 4; ++jj) {
          const int rr0 = 32 * rblk + 8 * jj + 4 * hi;
          half4_t tv;
          #pragma unroll
          for (int e = 0; e < 4; ++e) tv[e] = A0[jj][e] + A1[jj][e + 4];
          *(half4_t*)&Tg[eidx(tp, rr0)] = tv;
        }
      } else {
        floatx16 a1h, a1l, a2h, a2l;
        #pragma unroll
        for (int j = 0; j < 16; ++j) { a1h[j] = 0; a1l[j] = 0; a2h[j] = 0; a2l[j] = 0; }
        #pragma unroll
        for (int kq = 0; kq < 4; ++kq) {
          a1h = __builtin_amdgcn_mfma_f32_32x32x16_f16(A0[kq], Urh[kq], a1h, 0, 0, 0);
          a2h = __builtin_amdgcn_mfma_f32_32x32x16_f16(A1[kq], Uih[kq], a2h, 0, 0, 0);
          a1l = __builtin_amdgcn_mfma_f32_32x32x16_f16(A0[kq], Url[kq], a1l, 0, 0, 0);
          a2l = __builtin_amdgcn_mfma_f32_32x32x16_f16(A1[kq], Uil[kq], a2l, 0, 0, 0);
        }
        const float s1 = grp ? 1.0f : -1.0f;
        #pragma unroll
        for (int jj = 0; jj < 4; ++jj) {
          const int rr0 = 32 * rblk + 8 * jj + 4 * hi;
          half4_t tv;
          #pragma unroll
          for (int e = 0; e < 4; ++e) {
            const int j = 4 * jj + e;
            tv[e] = (_Float16)((a1h[j] + s1 * a2h[j]) + (a1l[j] + s1 * a2l[j]) * 0.00390625f);
          }
          *(half4_t*)&Tg[eidx(tp, rr0)] = tv;
        }
      }
    }
    if constexpr (ABL == 4) WAITONLY(); else BARX();

    // stage2
    {
      half8 B0[4], B1[4];
      const int p2 = 32 * rblk + l31;
      if constexpr (ABL == 2) {
        #pragma unroll
        for (int kq = 0; kq < 4; ++kq) {
          const _Float16 hs0 = (_Float16)rv[kq + 8];
          const _Float16 hs1 = (_Float16)rv[kq + 12];
          #pragma unroll
          for (int e = 0; e < 8; ++e) { B0[kq][e] = hs0; B1[kq][e] = hs1; }
        }
      } else {
        #pragma unroll
        for (int kq = 0; kq < 4; ++kq) {
          const int cc = 16 * kq + 8 * hi;
          half8 btr = *(const half8*)&Tr[eidx(p2, cc)];
          half8 bti = *(const half8*)&Ti[eidx(p2, cc)];
          if (grp == 0) { B0[kq] = btr; B1[kq] = bti; }
          else          { B0[kq] = bti; B1[kq] = btr; }
        }
      }
      if constexpr (ABL == 1) {
        #pragma unroll
        for (int j = 0; j < 16; ++j)
          rv[j] = fmaf((float)B0[j & 3][(j >> 2) & 7], 0.0625f, rv[j] * 0.5f);
      } else {
        floatx16 c1h, c1l, c2h, c2l;
        #pragma unroll
        for (int j = 0; j < 16; ++j) { c1h[j] = 0; c1l[j] = 0; c2h[j] = 0; c2l[j] = 0; }
        #pragma unroll
        for (int kq = 0; kq < 4; ++kq) {
          c1h = __builtin_amdgcn_mfma_f32_32x32x16_f16(Urh[kq], B0[kq], c1h, 0, 0, 0);
          c2h = __builtin_amdgcn_mfma_f32_32x32x16_f16(Uih[kq], B1[kq], c2h, 0, 0, 0);
          c1l = __builtin_amdgcn_mfma_f32_32x32x16_f16(Url[kq], B0[kq], c1l, 0, 0, 0);
          c2l = __builtin_amdgcn_mfma_f32_32x32x16_f16(Uil[kq], B1[kq], c2l, 0, 0, 0);
        }
        const float s2 = grp ? -1.0f : 1.0f;
        #pragma unroll
        for (int j = 0; j < 16; ++j)
          rv[j] = (c1h[j] + s2 * c2h[j]) + (c1l[j] + s2 * c2l[j]) * 0.00390625f;
      }
    }
  }

  // keep everything live; never stores (sigmoid < 1 always, opaque to compiler)
  #pragma unroll
  for (int j = 0; j < 16; ++j) asm volatile("" :: "v"(rv[j]));
  asm volatile("" :: "v"(Sig));
  if (g > 2.0f) out[0] = rv[0] + Sig;
}

// ================= K2: W = U^16 + 7 sequential chunk combines (R7) =============
__global__ __launch_bounds__(512, 1)
void qrnn_combine(const float* __restrict__ U_r, const float* __restrict__ U_i,
                  const float* __restrict__ lam_p, float* __restrict__ out) {
  __shared__ float Ga_r[64 * 68], Ga_i[64 * 68], Gb_r[64 * 68], Gb_i[64 * 68];
  __shared__ __align__(16) _Float16 Vr[4096], Vi[4096], Tr[4096], Ti[4096];
  __shared__ float red[8];

  const int b = blockIdx.x;
  const int tid = threadIdx.x;
  const int lane = tid & 63, hi = lane >> 5, l31 = lane & 31, w = tid >> 6;
  const int grp = w >> 2, rblk = (w >> 1) & 1, pblk = w & 1;
  const int prow = 32 * rblk + l31;

  const float g = 1.0f / (1.0f + expf(-lam_p[0]));
  const float g2 = g * g, g4 = g2 * g2, g8 = g4 * g4, g16 = g8 * g8;

  const int qr = tid >> 3, qc = (tid & 7) * 8;
  {
    *(float4_t*)&Ga_r[qr * 68 + qc]     = *(const float4_t*)(U_r + qr * 64 + qc);
    *(float4_t*)&Ga_r[qr * 68 + qc + 4] = *(const float4_t*)(U_r + qr * 64 + qc + 4);
    *(float4_t*)&Ga_i[qr * 68 + qc]     = *(const float4_t*)(U_i + qr * 64 + qc);
    *(float4_t*)&Ga_i[qr * 68 + qc + 4] = *(const float4_t*)(U_i + qr * 64 + qc + 4);
  }
  __syncthreads();

  #pragma unroll
  for (int it = 0; it < 4; ++it) {
    const float* sr = (it & 1) ? Gb_r : Ga_r;
    const float* si = (it & 1) ? Gb_i : Ga_i;
    float* dr = (it & 1) ? Ga_r : Gb_r;
    float* di = (it & 1) ? Ga_i : Gb_i;
    float cr[8], ci[8];
    #pragma unroll
    for (int e = 0; e < 8; ++e) { cr[e] = 0.0f; ci[e] = 0.0f; }
    for (int k = 0; k < 64; ++k) {
      const float ar = sr[qr * 68 + k];
      const float ai = si[qr * 68 + k];
      float4_t br0 = *(const float4_t*)&sr[k * 68 + qc];
      float4_t br1 = *(const float4_t*)&sr[k * 68 + qc + 4];
      float4_t bi0 = *(const float4_t*)&si[k * 68 + qc];
      float4_t bi1 = *(const float4_t*)&si[k * 68 + qc + 4];
      #pragma unroll
      for (int e = 0; e < 4; ++e) {
        cr[e]     += ar * br0[e] - ai * bi0[e];
        ci[e]     += ar * bi0[e] + ai * br0[e];
        cr[4 + e] += ar * br1[e] - ai * bi1[e];
        ci[4 + e] += ar * bi1[e] + ai * br1[e];
      }
    }
    float4_t s0, s1, s2, s3;
    #pragma unroll
    for (int e = 0; e < 4; ++e) { s0[e] = cr[e]; s1[e] = cr[4 + e]; s2[e] = ci[e]; s3[e] = ci[4 + e]; }
    *(float4_t*)&dr[qr * 68 + qc] = s0;  *(float4_t*)&dr[qr * 68 + qc + 4] = s1;
    *(float4_t*)&di[qr * 68 + qc] = s2;  *(float4_t*)&di[qr * 68 + qc + 4] = s3;
    __syncthreads();
  }

  half8 Wrh[4], Wrl[4], Wih[4], Wil[4];
  {
    const int row = 32 * pblk + l31;
    #pragma unroll
    for (int kq = 0; kq < 4; ++kq) {
      const int c0 = 16 * kq + 8 * hi;
      #pragma unroll
      for (int e = 0; e < 8; ++e) {
        const float wr = Ga_r[row * 68 + c0 + e];
        const float wi = Ga_i[row * 68 + c0 + e];
        _Float16 h;
        h = (_Float16)wr; Wrh[kq][e] = h; Wrl[kq][e] = (_Float16)((wr - (float)h) * 256.0f);
        h = (_Float16)wi; Wih[kq][e] = h; Wil[kq][e] = (_Float16)((wi - (float)h) * 256.0f);
      }
    }
  }

  float rv[16];
  #pragma unroll
  for (int j = 0; j < 16; ++j)
    rv[j] = (grp == 0 && prow == jcolf(j, pblk, hi)) ? (1.0f / 64.0f) : 0.0f;

  for (int c = 0; c < NC - 1; ++c) {
    float pv[16];
    {
      const float* ps = out + ((size_t)((grp ? NT : 0) + c * CL) * NB + b) * 4096;
      #pragma unroll
      for (int j = 0; j < 16; ++j) pv[j] = ps[prow * 64 + jcolf(j, pblk, hi)];
    }
    float ml = 0.0f;
    #pragma unroll
    for (int j = 0; j < 16; ++j) ml = fmaxf(ml, fabsf(rv[j]));
    #pragma unroll
    for (int d = 32; d >= 1; d >>= 1) ml = fmaxf(ml, __shfl_xor(ml, d, 64));
    if (lane == 0) red[w] = ml;
    __syncthreads();
    float mm = red[0];
    #pragma unroll
    for (int i = 1; i < 8; ++i) mm = fmaxf(mm, red[i]);
    int E = 0;
    if (mm > 0.0f) frexpf(mm, &E);
    const float al = ldexpf(1.0f, -E);
    const float fE = g16 * ldexpf(1.0f, E);

    {
      _Float16* Vg = grp ? Vi : Vr;
      #pragma unroll
      for (int j = 0; j < 16; ++j)
        Vg[eidx(jcolf(j, pblk, hi), prow)] = (_Float16)(al * rv[j]);
    }
    __syncthreads();

    {
      half8 A0[4], A1[4];
      const int rrow = 32 * rblk + l31;
      #pragma unroll
      for (int kq = 0; kq < 4; ++kq) {
        const int cc = 16 * kq + 8 * hi;
        half8 avr = *(const half8*)&Vr[eidx(rrow, cc)];
        half8 avi = *(const half8*)&Vi[eidx(rrow, cc)];
        if (grp == 0) { A0[kq] = avr; A1[kq] = avi; }
        else          { A0[kq] = avi; A1[kq] = avr; }
      }
      floatx16 a1h, a1l, a2h, a2l;
      #pragma unroll
      for (int j = 0; j < 16; ++j) { a1h[j] = 0; a1l[j] = 0; a2h[j] = 0; a2l[j] = 0; }
      #pragma unroll
      for (int kq = 0; kq < 4; ++kq) {
        a1h = __builtin_amdgcn_mfma_f32_32x32x16_f16(A0[kq], Wrh[kq], a1h, 0, 0, 0);
        a2h = __builtin_amdgcn_mfma_f32_32x32x16_f16(A1[kq], Wih[kq], a2h, 0, 0, 0);
        a1l = __builtin_amdgcn_mfma_f32_32x32x16_f16(A0[kq], Wrl[kq], a1l, 0, 0, 0);
        a2l = __builtin_amdgcn_mfma_f32_32x32x16_f16(A1[kq], Wil[kq], a2l, 0, 0, 0);
      }
      const float s1 = grp ? 1.0f : -1.0f;
      _Float16* Tg = grp ? Ti : Tr;
      const int tp = 32 * pblk + l31;
      #pragma unroll
      for (int jj = 0; jj < 4; ++jj) {
        const int rr0 = 32 * rblk + 8 * jj + 4 * hi;
        half4_t tv;
        #pragma unroll
        for (int e = 0; e < 4; ++e) {
          const int j = 4 * jj + e;
          tv[e] = (_Float16)((a1h[j] + s1 * a2h[j]) + (a1l[j] + s1 * a2l[j]) * 0.00390625f);
        }
        *(half4_t*)&Tg[eidx(tp, rr0)] = tv;
      }
    }
    __syncthreads();

    {
      half8 B0[4], B1[4];
      const int p2 = 32 * rblk + l31;
      #pragma unroll
      for (int kq = 0; kq < 4; ++kq) {
        const int cc = 16 * kq + 8 * hi;
        half8 btr = *(const half8*)&Tr[eidx(p2, cc)];
        half8 bti = *(const half8*)&Ti[eidx(p2, cc)];
        if (grp == 0) { B0[kq] = btr; B1[kq] = bti; }
        else          { B0[kq] = bti; B1[kq] = btr; }
      }
      floatx16 c1h, c1l, c2h, c2l;
      #pragma unroll
      for (int j = 0; j < 16; ++j) { c1h[j] = 0; c1l[j] = 0; c2h[j] = 0; c2l[j] = 0; }
      #pragma unroll
      for (int kq = 0; kq < 4; ++kq) {
        c1h = __builtin_amdgcn_mfma_f32_32x32x16_f16(Wrh[kq], B0[kq], c1h, 0, 0, 0);
        c2h = __builtin_amdgcn_mfma_f32_32x32x16_f16(Wih[kq], B1[kq], c2h, 0, 0, 0);
        c1l = __builtin_amdgcn_mfma_f32_32x32x16_f16(Wrl[kq], B0[kq], c1l, 0, 0, 0);
        c2l = __builtin_amdgcn_mfma_f32_32x32x16_f16(Wil[kq], B1[kq], c2l, 0, 0, 0);
      }
      const float s2 = grp ? -1.0f : 1.0f;
      #pragma unroll
      for (int j = 0; j < 16; ++j) {
        const float rvS = (c1h[j] + s2 * c2h[j]) + (c1l[j] + s2 * c2l[j]) * 0.00390625f;
        rv[j] = fE * rvS + pv[j];
      }
    }
    {
      float* hs = out + ((size_t)((grp ? NT : 0) + (c + 1) * CL + 1) * NB + b) * 4096;
      #pragma unroll
      for (int j = 0; j < 16; ++j) hs[prow * 64 + jcolf(j, pblk, hi)] = rv[j];
    }
    __syncthreads();
  }
}

extern "C" void kernel_launch(void* const* d_in, const int* in_sizes, int n_in,
                              void* d_out, int out_size, void* d_ws, size_t ws_size,
                              hipStream_t stream) {
  (void)in_sizes; (void)n_in; (void)out_size; (void)d_ws; (void)ws_size;
  const float* dr = (const float*)d_in[0];
  const float* di = (const float*)d_in[1];
  const float* ur = (const float*)d_in[2];
  const float* ui = (const float*)d_in[3];
  const float* lm = (const float*)d_in[4];
  float* o = (float*)d_out;
  // --- ablation probes (store-free, timing read from rocprof per-dispatch) ---
  qrnn_abl<1><<<dim3(NB * NC), dim3(512), 0, stream>>>(dr, di, ur, ui, lm, o);  // no MFMA
  qrnn_abl<2><<<dim3(NB * NC), dim3(512), 0, stream>>>(dr, di, ur, ui, lm, o);  // no V/T ds_read
  qrnn_abl<4><<<dim3(NB * NC), dim3(512), 0, stream>>>(dr, di, ur, ui, lm, o);  // no s_barrier
  // --- real computation (R7 structure) ---
  qrnn_scan<false><<<dim3(NB * NC), dim3(512), 0, stream>>>(dr, di, ur, ui, lm, o);
  qrnn_combine<<<dim3(NB), dim3(512), 0, stream>>>(ur, ui, lm, o);
  qrnn_scan<true><<<dim3(NB * NC), dim3(512), 0, stream>>>(dr, di, ur, ui, lm, o);
}

// Round 10
// 300.905 us; speedup vs baseline: 13.8631x; 1.7121x over previous
//
#include <hip/hip_runtime.h>
#include <math.h>

typedef _Float16 half8 __attribute__((ext_vector_type(8)));
typedef _Float16 half4_t __attribute__((ext_vector_type(4)));
typedef float floatx16 __attribute__((ext_vector_type(16)));
typedef float float4_t __attribute__((ext_vector_type(4)));

#define NT 128
#define NB 64
#define NC 8
#define CL 16

// element index with 8-f16 (16B) unit XOR swizzle inside a 64-f16 (128B) row
__device__ __forceinline__ int eidx(int row, int col) {
  return row * 64 + ((((col >> 3) ^ row) & 7) << 3) + (col & 7);
}
__device__ __forceinline__ int jcolf(int j, int pblk, int hi) {
  return 32 * pblk + (j & 3) + 8 * (j >> 2) + 4 * hi;
}

// LDS-only barrier (globals never carry intra-kernel cross-wave data here)
#define BARX() do {                                        \
  asm volatile("s_waitcnt lgkmcnt(0)" ::: "memory");       \
  __builtin_amdgcn_s_barrier();                            \
  __builtin_amdgcn_sched_barrier(0);                       \
} while (0)

// ---------------- chunk scan: PASS3=false -> emit p_c ; PASS3=true -> emit out ----
// Register diet vs R7: U frags in LDS (not 64 VGPRs), single acc pair per stage
// (32 not 64 AGPRs), x gathered straight to regs (no X LDS). Target <=128 unified
// regs -> 4 waves/SIMD -> 2 blocks/CU resident (R9: AGPRs pushed us to 1).
template<bool PASS3>
__global__ __launch_bounds__(512, 4)
void qrnn_scan(const float* __restrict__ data_r, const float* __restrict__ data_i,
               const float* __restrict__ U_r, const float* __restrict__ U_i,
               const float* __restrict__ lam_p, float* __restrict__ out) {
  __shared__ __align__(16) _Float16 Uhr[4096], Uhi_[4096], Ulr[4096], Uli_[4096];
  __shared__ __align__(16) _Float16 Vr[4096], Vi[4096];
  __shared__ __align__(16) _Float16 Tr[4096], Ti[4096];
  __shared__ __align__(16) float red[8];

  const int bx = blockIdx.x;
  const int b  = bx & (NB - 1);
  const int c  = bx >> 6;          // chunk id 0..NC-1
  const int t0 = c * CL;
  const int tid = threadIdx.x;
  const int lane = tid & 63, hi = lane >> 5, l31 = lane & 31, w = tid >> 6;
  const int grp = w >> 2, rblk = (w >> 1) & 1, pblk = w & 1;
  const int prow = 32 * rblk + l31;
  const int urow = 32 * pblk + l31;

  const float g = 1.0f / (1.0f + expf(-lam_p[0]));

  // ---- cooperative U staging -> LDS (hi + lo*256 split), swizzled frag layout ----
  const int dq = tid >> 3, dr0 = (tid & 7) * 8;
  {
    const float4_t a0 = *(const float4_t*)(U_r + dq * 64 + dr0);
    const float4_t a1 = *(const float4_t*)(U_r + dq * 64 + dr0 + 4);
    const float4_t b0 = *(const float4_t*)(U_i + dq * 64 + dr0);
    const float4_t b1 = *(const float4_t*)(U_i + dq * 64 + dr0 + 4);
    half8 hr, lr, hm, lm;
    #pragma unroll
    for (int e = 0; e < 4; ++e) {
      _Float16 h;
      h = (_Float16)a0[e]; hr[e]     = h; lr[e]     = (_Float16)((a0[e] - (float)h) * 256.0f);
      h = (_Float16)a1[e]; hr[4 + e] = h; lr[4 + e] = (_Float16)((a1[e] - (float)h) * 256.0f);
      h = (_Float16)b0[e]; hm[e]     = h; lm[e]     = (_Float16)((b0[e] - (float)h) * 256.0f);
      h = (_Float16)b1[e]; hm[4 + e] = h; lm[4 + e] = (_Float16)((b1[e] - (float)h) * 256.0f);
    }
    const int off = eidx(dq, dr0);
    *(half8*)&Uhr[off]  = hr;  *(half8*)&Ulr[off]  = lr;
    *(half8*)&Uhi_[off] = hm;  *(half8*)&Uli_[off] = lm;
  }

  // ---- initial state ----
  float rv[16];
  if constexpr (PASS3) {
    if (c == 0) {
      #pragma unroll
      for (int j = 0; j < 16; ++j)
        rv[j] = (grp == 0 && prow == jcolf(j, pblk, hi)) ? (1.0f / 64.0f) : 0.0f;
    } else {
      const float* hs = out + ((size_t)((grp ? NT : 0) + t0 + 1) * NB + b) * 4096;
      #pragma unroll
      for (int j = 0; j < 16; ++j)
        rv[j] = hs[prow * 64 + jcolf(j, pblk, hi)];
    }
  } else {
    #pragma unroll
    for (int j = 0; j < 16; ++j) rv[j] = 0.0f;
  }
  {
    float ml = 0.0f;
    #pragma unroll
    for (int j = 0; j < 16; ++j) ml = fmaxf(ml, fabsf(rv[j]));
    #pragma unroll
    for (int d = 32; d >= 1; d >>= 1) ml = fmaxf(ml, __shfl_xor(ml, d, 64));
    if (lane == 0) red[w] = ml;
  }

  // x gather: thread consumes exactly x[prow][32*pblk + 8*jj + 4*hi + e]
  const float* __restrict__ xsrc = grp ? data_i : data_r;
  const size_t xoff = (size_t)prow * 64 + 32 * pblk + 4 * hi;
  float4_t px[4];
  {
    const float* xp = xsrc + ((size_t)t0 * NB + b) * 4096 + xoff;
    #pragma unroll
    for (int jj = 0; jj < 4; ++jj) px[jj] = *(const float4_t*)(xp + 8 * jj);
  }
  BARX();  // U, red published

  float Sig, alpha = 1.0f, alphainv = 1.0f;
  {
    float4_t r0 = *(const float4_t*)&red[0];
    float4_t r1 = *(const float4_t*)&red[4];
    float mm = fmaxf(fmaxf(fmaxf(r0[0], r0[1]), fmaxf(r0[2], r0[3])),
                     fmaxf(fmaxf(r1[0], r1[1]), fmaxf(r1[2], r1[3])));
    int E0 = 0;
    if (mm > 0.0f) frexpf(mm, &E0);
    const float sc = ldexpf(1.0f, -E0);
    #pragma unroll
    for (int j = 0; j < 16; ++j) rv[j] *= sc;   // normalize entry state
    Sig = ldexpf(1.0f, E0);                     // true h = Sig * rv
  }

  for (int s = 0; s < CL; ++s) {
    // ===== MIX: V^T from rv + register x; publish wave max (stale-1 alpha) =====
    {
      const float ga = g * alpha;
      const float kx = (1.0f - g) * alpha / Sig;
      _Float16* Vg = grp ? Vi : Vr;
      #pragma unroll
      for (int jj = 0; jj < 4; ++jj) {
        const int j0 = 32 * pblk + 8 * jj + 4 * hi;
        #pragma unroll
        for (int e = 0; e < 4; ++e) {
          const float vv = ga * rv[4 * jj + e] + kx * px[jj][e];
          Vg[eidx(j0 + e, prow)] = (_Float16)vv;   // V^T
        }
      }
      float m0[8];
      #pragma unroll
      for (int e = 0; e < 8; ++e) m0[e] = fmaxf(fabsf(rv[e]), fabsf(rv[e + 8]));
      #pragma unroll
      for (int e = 0; e < 4; ++e) m0[e] = fmaxf(m0[e], m0[e + 4]);
      float ml = fmaxf(fmaxf(m0[0], m0[1]), fmaxf(m0[2], m0[3]));
      #pragma unroll
      for (int d = 32; d >= 1; d >>= 1) ml = fmaxf(ml, __shfl_xor(ml, d, 64));
      if (lane == 0) red[w] = ml;
    }
    BARX();  // bar1: V, red published

    // ===== REGION2: x gather for s+1, out stores, alpha update, stage1 =====
    if (s + 1 < CL) {
      const float* xp = xsrc + ((size_t)(t0 + s + 1) * NB + b) * 4096 + xoff;
      #pragma unroll
      for (int jj = 0; jj < 4; ++jj) px[jj] = *(const float4_t*)(xp + 8 * jj);
    }
    if constexpr (PASS3) {  // true h^(s) = Sig_old * rv
      if (s > 0) {
        float* oR = out + ((size_t)(t0 + s - 1) * NB + b) * 4096
                        + (grp ? (size_t)NT * NB * 4096 : 0) + (size_t)(prow * 64);
        #pragma unroll
        for (int jj = 0; jj < 4; ++jj) {
          const int j0 = 32 * pblk + 8 * jj + 4 * hi;
          float4_t ov;
          #pragma unroll
          for (int e = 0; e < 4; ++e) ov[e] = Sig * rv[4 * jj + e];
          *(float4_t*)(oR + j0) = ov;
        }
      }
    }
    Sig *= alphainv;
    {
      float4_t r0 = *(const float4_t*)&red[0];
      float4_t r1 = *(const float4_t*)&red[4];
      float mm = fmaxf(fmaxf(fmaxf(r0[0], r0[1]), fmaxf(r0[2], r0[3])),
                       fmaxf(fmaxf(r1[0], r1[1]), fmaxf(r1[2], r1[3])));
      int E = 0;
      if (mm > 0.0f) frexpf(mm, &E);
      alpha = ldexpf(1.0f, -E);
      alphainv = ldexpf(1.0f, E);
    }

    // ---- stage1: t^T = V^T * U^T ; single hi+lo acc, signs folded into frags ----
    // grp0: t_r = vr*Ur - vi*Ui -> f0=vr, f1=-vi ; grp1: t_i = vi*Ur + vr*Ui
    {
      floatx16 ah, al;
      #pragma unroll
      for (int j = 0; j < 16; ++j) { ah[j] = 0.0f; al[j] = 0.0f; }
      #pragma unroll
      for (int kq = 0; kq < 4; ++kq) {
        const int cc = 16 * kq + 8 * hi;
        const int vo = eidx(prow, cc);
        const int uo = eidx(urow, cc);
        half8 avr = *(const half8*)&Vr[vo];
        half8 avi = *(const half8*)&Vi[vo];
        half8 f0 = grp ? avi : avr;
        half8 f1 = grp ? avr : -avi;
        ah = __builtin_amdgcn_mfma_f32_32x32x16_f16(f0, *(const half8*)&Uhr[uo], ah, 0, 0, 0);
        ah = __builtin_amdgcn_mfma_f32_32x32x16_f16(f1, *(const half8*)&Uhi_[uo], ah, 0, 0, 0);
        al = __builtin_amdgcn_mfma_f32_32x32x16_f16(f0, *(const half8*)&Ulr[uo], al, 0, 0, 0);
        al = __builtin_amdgcn_mfma_f32_32x32x16_f16(f1, *(const half8*)&Uli_[uo], al, 0, 0, 0);
      }
      _Float16* Tg = grp ? Ti : Tr;
      const int tp = 32 * pblk + l31;   // T[p][r]
      #pragma unroll
      for (int jj = 0; jj < 4; ++jj) {
        const int rr0 = 32 * rblk + 8 * jj + 4 * hi;
        half4_t tv;
        #pragma unroll
        for (int e = 0; e < 4; ++e) {
          const int j = 4 * jj + e;
          tv[e] = (_Float16)(ah[j] + al[j] * 0.00390625f);
        }
        *(half4_t*)&Tg[eidx(tp, rr0)] = tv;
      }
    }
    BARX();  // bar2: T published

    // ---- stage2: h'^T = U * t^T -> rv ----
    // grp0: h_r = Ur*tr + Ui*ti ; grp1: h_i = Ur*ti - Ui*tr -> f1 = -tr
    {
      floatx16 ch, cl;
      #pragma unroll
      for (int j = 0; j < 16; ++j) { ch[j] = 0.0f; cl[j] = 0.0f; }
      const int p2 = 32 * rblk + l31;
      #pragma unroll
      for (int kq = 0; kq < 4; ++kq) {
        const int cc = 16 * kq + 8 * hi;
        const int to = eidx(p2, cc);
        const int uo = eidx(urow, cc);
        half8 btr = *(const half8*)&Tr[to];
        half8 bti = *(const half8*)&Ti[to];
        half8 f0 = grp ? bti : btr;
        half8 f1 = grp ? -btr : bti;
        ch = __builtin_amdgcn_mfma_f32_32x32x16_f16(*(const half8*)&Uhr[uo], f0, ch, 0, 0, 0);
        ch = __builtin_amdgcn_mfma_f32_32x32x16_f16(*(const half8*)&Uhi_[uo], f1, ch, 0, 0, 0);
        cl = __builtin_amdgcn_mfma_f32_32x32x16_f16(*(const half8*)&Ulr[uo], f0, cl, 0, 0, 0);
        cl = __builtin_amdgcn_mfma_f32_32x32x16_f16(*(const half8*)&Uli_[uo], f1, cl, 0, 0, 0);
      }
      #pragma unroll
      for (int j = 0; j < 16; ++j)
        rv[j] = ch[j] + cl[j] * 0.00390625f;
    }
  }

  // ---- epilogue: direct store of final state (true h = Sig * rv) ----
  {
    const int trow = PASS3 ? (t0 + CL - 1) : t0;
    float* eR = out + ((size_t)trow * NB + b) * 4096
                    + (grp ? (size_t)NT * NB * 4096 : 0) + (size_t)(prow * 64);
    #pragma unroll
    for (int jj = 0; jj < 4; ++jj) {
      const int j0 = 32 * pblk + 8 * jj + 4 * hi;
      float4_t ov;
      #pragma unroll
      for (int e = 0; e < 4; ++e) ov[e] = Sig * rv[4 * jj + e];
      *(float4_t*)(eR + j0) = ov;
    }
  }
}

// ---------------- K2: W = U^16 (4 LDS squarings) + 7 sequential chunk combines ----
__global__ __launch_bounds__(512, 1)
void qrnn_combine(const float* __restrict__ U_r, const float* __restrict__ U_i,
                  const float* __restrict__ lam_p, float* __restrict__ out) {
  __shared__ float Ga_r[64 * 68], Ga_i[64 * 68], Gb_r[64 * 68], Gb_i[64 * 68];
  __shared__ __align__(16) _Float16 Vr[4096], Vi[4096], Tr[4096], Ti[4096];
  __shared__ float red[8];

  const int b = blockIdx.x;
  const int tid = threadIdx.x;
  const int lane = tid & 63, hi = lane >> 5, l31 = lane & 31, w = tid >> 6;
  const int grp = w >> 2, rblk = (w >> 1) & 1, pblk = w & 1;
  const int prow = 32 * rblk + l31;

  const float g = 1.0f / (1.0f + expf(-lam_p[0]));
  const float g2 = g * g, g4 = g2 * g2, g8 = g4 * g4, g16 = g8 * g8;

  const int qr = tid >> 3, qc = (tid & 7) * 8;
  {
    *(float4_t*)&Ga_r[qr * 68 + qc]     = *(const float4_t*)(U_r + qr * 64 + qc);
    *(float4_t*)&Ga_r[qr * 68 + qc + 4] = *(const float4_t*)(U_r + qr * 64 + qc + 4);
    *(float4_t*)&Ga_i[qr * 68 + qc]     = *(const float4_t*)(U_i + qr * 64 + qc);
    *(float4_t*)&Ga_i[qr * 68 + qc + 4] = *(const float4_t*)(U_i + qr * 64 + qc + 4);
  }
  __syncthreads();

  #pragma unroll
  for (int it = 0; it < 4; ++it) {
    const float* sr = (it & 1) ? Gb_r : Ga_r;
    const float* si = (it & 1) ? Gb_i : Ga_i;
    float* dr = (it & 1) ? Ga_r : Gb_r;
    float* di = (it & 1) ? Ga_i : Gb_i;
    float cr[8], ci[8];
    #pragma unroll
    for (int e = 0; e < 8; ++e) { cr[e] = 0.0f; ci[e] = 0.0f; }
    for (int k = 0; k < 64; ++k) {
      const float ar = sr[qr * 68 + k];
      const float ai = si[qr * 68 + k];
      float4_t br0 = *(const float4_t*)&sr[k * 68 + qc];
      float4_t br1 = *(const float4_t*)&sr[k * 68 + qc + 4];
      float4_t bi0 = *(const float4_t*)&si[k * 68 + qc];
      float4_t bi1 = *(const float4_t*)&si[k * 68 + qc + 4];
      #pragma unroll
      for (int e = 0; e < 4; ++e) {
        cr[e]     += ar * br0[e] - ai * bi0[e];
        ci[e]     += ar * bi0[e] + ai * br0[e];
        cr[4 + e] += ar * br1[e] - ai * bi1[e];
        ci[4 + e] += ar * bi1[e] + ai * br1[e];
      }
    }
    float4_t s0, s1, s2, s3;
    #pragma unroll
    for (int e = 0; e < 4; ++e) { s0[e] = cr[e]; s1[e] = cr[4 + e]; s2[e] = ci[e]; s3[e] = ci[4 + e]; }
    *(float4_t*)&dr[qr * 68 + qc] = s0;  *(float4_t*)&dr[qr * 68 + qc + 4] = s1;
    *(float4_t*)&di[qr * 68 + qc] = s2;  *(float4_t*)&di[qr * 68 + qc + 4] = s3;
    __syncthreads();
  }

  half8 Wrh[4], Wrl[4], Wih[4], Wil[4];
  {
    const int row = 32 * pblk + l31;
    #pragma unroll
    for (int kq = 0; kq < 4; ++kq) {
      const int c0 = 16 * kq + 8 * hi;
      #pragma unroll
      for (int e = 0; e < 8; ++e) {
        const float wr = Ga_r[row * 68 + c0 + e];
        const float wi = Ga_i[row * 68 + c0 + e];
        _Float16 h;
        h = (_Float16)wr; Wrh[kq][e] = h; Wrl[kq][e] = (_Float16)((wr - (float)h) * 256.0f);
        h = (_Float16)wi; Wih[kq][e] = h; Wil[kq][e] = (_Float16)((wi - (float)h) * 256.0f);
      }
    }
  }

  float rv[16];
  #pragma unroll
  for (int j = 0; j < 16; ++j)
    rv[j] = (grp == 0 && prow == jcolf(j, pblk, hi)) ? (1.0f / 64.0f) : 0.0f;

  for (int c = 0; c < NC - 1; ++c) {
    float pv[16];
    {
      const float* ps = out + ((size_t)((grp ? NT : 0) + c * CL) * NB + b) * 4096;
      #pragma unroll
      for (int j = 0; j < 16; ++j) pv[j] = ps[prow * 64 + jcolf(j, pblk, hi)];
    }
    float ml = 0.0f;
    #pragma unroll
    for (int j = 0; j < 16; ++j) ml = fmaxf(ml, fabsf(rv[j]));
    #pragma unroll
    for (int d = 32; d >= 1; d >>= 1) ml = fmaxf(ml, __shfl_xor(ml, d, 64));
    if (lane == 0) red[w] = ml;
    __syncthreads();
    float mm = red[0];
    #pragma unroll
    for (int i = 1; i < 8; ++i) mm = fmaxf(mm, red[i]);
    int E = 0;
    if (mm > 0.0f) frexpf(mm, &E);
    const float al = ldexpf(1.0f, -E);
    const float fE = g16 * ldexpf(1.0f, E);

    {
      _Float16* Vg = grp ? Vi : Vr;
      #pragma unroll
      for (int j = 0; j < 16; ++j)
        Vg[eidx(jcolf(j, pblk, hi), prow)] = (_Float16)(al * rv[j]);
    }
    __syncthreads();

    {
      half8 A0[4], A1[4];
      const int rrow = 32 * rblk + l31;
      #pragma unroll
      for (int kq = 0; kq < 4; ++kq) {
        const int cc = 16 * kq + 8 * hi;
        half8 avr = *(const half8*)&Vr[eidx(rrow, cc)];
        half8 avi = *(const half8*)&Vi[eidx(rrow, cc)];
        if (grp == 0) { A0[kq] = avr; A1[kq] = avi; }
        else          { A0[kq] = avi; A1[kq] = avr; }
      }
      floatx16 a1h, a1l, a2h, a2l;
      #pragma unroll
      for (int j = 0; j < 16; ++j) { a1h[j] = 0; a1l[j] = 0; a2h[j] = 0; a2l[j] = 0; }
      #pragma unroll
      for (int kq = 0; kq < 4; ++kq) {
        a1h = __builtin_amdgcn_mfma_f32_32x32x16_f16(A0[kq], Wrh[kq], a1h, 0, 0, 0);
        a2h = __builtin_amdgcn_mfma_f32_32x32x16_f16(A1[kq], Wih[kq], a2h, 0, 0, 0);
        a1l = __builtin_amdgcn_mfma_f32_32x32x16_f16(A0[kq], Wrl[kq], a1l, 0, 0, 0);
        a2l = __builtin_amdgcn_mfma_f32_32x32x16_f16(A1[kq], Wil[kq], a2l, 0, 0, 0);
      }
      const float s1 = grp ? 1.0f : -1.0f;
      _Float16* Tg = grp ? Ti : Tr;
      const int tp = 32 * pblk + l31;
      #pragma unroll
      for (int jj = 0; jj < 4; ++jj) {
        const int rr0 = 32 * rblk + 8 * jj + 4 * hi;
        half4_t tv;
        #pragma unroll
        for (int e = 0; e < 4; ++e) {
          const int j = 4 * jj + e;
          tv[e] = (_Float16)((a1h[j] + s1 * a2h[j]) + (a1l[j] + s1 * a2l[j]) * 0.00390625f);
        }
        *(half4_t*)&Tg[eidx(tp, rr0)] = tv;
      }
    }
    __syncthreads();

    {
      half8 B0[4], B1[4];
      const int p2 = 32 * rblk + l31;
      #pragma unroll
      for (int kq = 0; kq < 4; ++kq) {
        const int cc = 16 * kq + 8 * hi;
        half8 btr = *(const half8*)&Tr[eidx(p2, cc)];
        half8 bti = *(const half8*)&Ti[eidx(p2, cc)];
        if (grp == 0) { B0[kq] = btr; B1[kq] = bti; }
        else          { B0[kq] = bti; B1[kq] = btr; }
      }
      floatx16 c1h, c1l, c2h, c2l;
      #pragma unroll
      for (int j = 0; j < 16; ++j) { c1h[j] = 0; c1l[j] = 0; c2h[j] = 0; c2l[j] = 0; }
      #pragma unroll
      for (int kq = 0; kq < 4; ++kq) {
        c1h = __builtin_amdgcn_mfma_f32_32x32x16_f16(Wrh[kq], B0[kq], c1h, 0, 0, 0);
        c2h = __builtin_amdgcn_mfma_f32_32x32x16_f16(Wih[kq], B1[kq], c2h, 0, 0, 0);
        c1l = __builtin_amdgcn_mfma_f32_32x32x16_f16(Wrl[kq], B0[kq], c1l, 0, 0, 0);
        c2l = __builtin_amdgcn_mfma_f32_32x32x16_f16(Wil[kq], B1[kq], c2l, 0, 0, 0);
      }
      const float s2 = grp ? -1.0f : 1.0f;
      #pragma unroll
      for (int j = 0; j < 16; ++j) {
        const float rvS = (c1h[j] + s2 * c2h[j]) + (c1l[j] + s2 * c2l[j]) * 0.00390625f;
        rv[j] = fE * rvS + pv[j];
      }
    }
    {
      float* hs = out + ((size_t)((grp ? NT : 0) + (c + 1) * CL + 1) * NB + b) * 4096;
      #pragma unroll
      for (int j = 0; j < 16; ++j) hs[prow * 64 + jcolf(j, pblk, hi)] = rv[j];
    }
    __syncthreads();
  }
}

extern "C" void kernel_launch(void* const* d_in, const int* in_sizes, int n_in,
                              void* d_out, int out_size, void* d_ws, size_t ws_size,
                              hipStream_t stream) {
  (void)in_sizes; (void)n_in; (void)out_size; (void)d_ws; (void)ws_size;
  const float* dr = (const float*)d_in[0];
  const float* di = (const float*)d_in[1];
  const float* ur = (const float*)d_in[2];
  const float* ui = (const float*)d_in[3];
  const float* lm = (const float*)d_in[4];
  float* o = (float*)d_out;
  qrnn_scan<false><<<dim3(NB * NC), dim3(512), 0, stream>>>(dr, di, ur, ui, lm, o);
  qrnn_combine<<<dim3(NB), dim3(512), 0, stream>>>(ur, ui, lm, o);
  qrnn_scan<true><<<dim3(NB * NC), dim3(512), 0, stream>>>(dr, di, ur, ui, lm, o);
}

// Round 11
// 289.098 us; speedup vs baseline: 14.4293x; 1.0408x over previous
//
#include <hip/hip_runtime.h>
#include <math.h>

typedef _Float16 half8 __attribute__((ext_vector_type(8)));
typedef _Float16 half4_t __attribute__((ext_vector_type(4)));
typedef float floatx16 __attribute__((ext_vector_type(16)));
typedef float float4_t __attribute__((ext_vector_type(4)));

#define NT 128
#define NB 64
#define NC 8
#define CL 16

// ---- addrspace(1) access: force global_* (vmcnt-only) encoding ----
typedef __attribute__((address_space(1))) float gfloat;
typedef __attribute__((address_space(1))) float4_t gfloat4;
__device__ __forceinline__ float4_t gload4(const float* p) {
  return *(const gfloat4*)(unsigned long long)p;
}
__device__ __forceinline__ float gload1(const float* p) {
  return *(const gfloat*)(unsigned long long)p;
}
__device__ __forceinline__ void gstore4(float* p, float4_t v) {
  *(gfloat4*)(unsigned long long)p = v;
}
__device__ __forceinline__ void gstore1(float* p, float v) {
  *(gfloat*)(unsigned long long)p = v;
}

// element index with 8-f16 (16B) unit XOR swizzle inside a 64-f16 (128B) row (V/T)
__device__ __forceinline__ int eidx(int row, int col) {
  return row * 64 + ((((col >> 3) ^ row) & 7) << 3) + (col & 7);
}
// U fragment store, column-block-major: lanes (consecutive rows) read consecutive
// 16B lines -> zero extra bank conflicts on the hot stage reads.
__device__ __forceinline__ int uidx(int row, int cb) { return (cb * 64 + row) * 8; }
__device__ __forceinline__ int jcolf(int j, int pblk, int hi) {
  return 32 * pblk + (j & 3) + 8 * (j >> 2) + 4 * hi;
}

// alpha = 2^-E, alphainv = 2^E with mm = m*2^E, m in [0.5,1)  (branch-free frexp)
__device__ __forceinline__ void alpha_from_max(float mm, float& alpha, float& alphainv) {
  unsigned eb = (__float_as_uint(mm) >> 23) & 0xFFu;
  eb = (eb == 0u) ? 126u : eb;             // mm==0 or denormal -> E=0
  alpha    = __uint_as_float((253u - eb) << 23);
  alphainv = __uint_as_float((eb + 1u) << 23);
}

// LDS-only barrier (with AS1 globals, lgkmcnt tracks only LDS here)
#define BARX() do {                                        \
  asm volatile("s_waitcnt lgkmcnt(0)" ::: "memory");       \
  __builtin_amdgcn_s_barrier();                            \
  __builtin_amdgcn_sched_barrier(0);                       \
} while (0)

// ---------------- chunk scan: PASS3=false -> emit p_c ; PASS3=true -> emit out ----
template<bool PASS3>
__global__ __launch_bounds__(512, 4)
void qrnn_scan(const float* __restrict__ data_r, const float* __restrict__ data_i,
               const float* __restrict__ U_r, const float* __restrict__ U_i,
               const float* __restrict__ lam_p, float* __restrict__ out) {
  __shared__ __align__(16) _Float16 Uhr[4096], Uhi_[4096], Ulr[4096], Uli_[4096];
  __shared__ __align__(16) _Float16 Vr[4096], Vi[4096];
  __shared__ __align__(16) _Float16 Tr[4096], Ti[4096];
  __shared__ __align__(16) float red[8];

  const int bx = blockIdx.x;
  const int b  = bx & (NB - 1);
  const int c  = bx >> 6;          // chunk id 0..NC-1
  const int t0 = c * CL;
  const int tid = threadIdx.x;
  const int lane = tid & 63, hi = lane >> 5, l31 = lane & 31, w = tid >> 6;
  const int grp = w >> 2, rblk = (w >> 1) & 1, pblk = w & 1;
  const int prow = 32 * rblk + l31;
  const int urow = 32 * pblk + l31;

  const float g = 1.0f / (1.0f + expf(-lam_p[0]));

  // ---- cooperative U staging -> LDS (hi + lo*256 split), col-block-major ----
  const int dq = tid >> 3, cb0 = tid & 7, dr0 = cb0 * 8;
  {
    const float4_t a0 = gload4(U_r + dq * 64 + dr0);
    const float4_t a1 = gload4(U_r + dq * 64 + dr0 + 4);
    const float4_t b0 = gload4(U_i + dq * 64 + dr0);
    const float4_t b1 = gload4(U_i + dq * 64 + dr0 + 4);
    half8 hr, lr, hm, lm;
    #pragma unroll
    for (int e = 0; e < 4; ++e) {
      _Float16 h;
      h = (_Float16)a0[e]; hr[e]     = h; lr[e]     = (_Float16)((a0[e] - (float)h) * 256.0f);
      h = (_Float16)a1[e]; hr[4 + e] = h; lr[4 + e] = (_Float16)((a1[e] - (float)h) * 256.0f);
      h = (_Float16)b0[e]; hm[e]     = h; lm[e]     = (_Float16)((b0[e] - (float)h) * 256.0f);
      h = (_Float16)b1[e]; hm[4 + e] = h; lm[4 + e] = (_Float16)((b1[e] - (float)h) * 256.0f);
    }
    const int off = uidx(dq, cb0);
    *(half8*)&Uhr[off]  = hr;  *(half8*)&Ulr[off]  = lr;
    *(half8*)&Uhi_[off] = hm;  *(half8*)&Uli_[off] = lm;
  }

  // ---- initial state ----
  float rv[16];
  if constexpr (PASS3) {
    if (c == 0) {
      #pragma unroll
      for (int j = 0; j < 16; ++j)
        rv[j] = (grp == 0 && prow == jcolf(j, pblk, hi)) ? (1.0f / 64.0f) : 0.0f;
    } else {
      const float* hs = out + ((size_t)((grp ? NT : 0) + t0 + 1) * NB + b) * 4096;
      #pragma unroll
      for (int j = 0; j < 16; ++j)
        rv[j] = gload1(hs + prow * 64 + jcolf(j, pblk, hi));
    }
  } else {
    #pragma unroll
    for (int j = 0; j < 16; ++j) rv[j] = 0.0f;
  }
  {
    float ml = 0.0f;
    #pragma unroll
    for (int j = 0; j < 16; ++j) ml = fmaxf(ml, fabsf(rv[j]));
    #pragma unroll
    for (int d = 32; d >= 1; d >>= 1) ml = fmaxf(ml, __shfl_xor(ml, d, 64));
    if (lane == 0) red[w] = ml;
  }

  // x gather: thread consumes exactly x[prow][32*pblk + 8*jj + 4*hi + e]
  const float* __restrict__ xsrc = grp ? data_i : data_r;
  const size_t xoff = (size_t)prow * 64 + 32 * pblk + 4 * hi;
  float4_t px[4];
  {
    const float* xp = xsrc + ((size_t)t0 * NB + b) * 4096 + xoff;
    #pragma unroll
    for (int jj = 0; jj < 4; ++jj) px[jj] = gload4(xp + 8 * jj);
  }
  BARX();  // U, red published

  float Sig, alpha = 1.0f, alphainv = 1.0f;
  {
    float4_t r0 = *(const float4_t*)&red[0];
    float4_t r1 = *(const float4_t*)&red[4];
    float mm = fmaxf(fmaxf(fmaxf(r0[0], r0[1]), fmaxf(r0[2], r0[3])),
                     fmaxf(fmaxf(r1[0], r1[1]), fmaxf(r1[2], r1[3])));
    float sc;
    alpha_from_max(mm, sc, Sig);   // sc = 2^-E0, Sig = 2^E0
    #pragma unroll
    for (int j = 0; j < 16; ++j) rv[j] *= sc;   // normalize entry state
  }

  for (int s = 0; s < CL; ++s) {
    // ===== MIX: V^T from rv + register x; publish wave max (stale-1 alpha) =====
    {
      const float ga = g * alpha;
      const float kx = (1.0f - g) * alpha / Sig;
      _Float16* Vg = grp ? Vi : Vr;
      #pragma unroll
      for (int jj = 0; jj < 4; ++jj) {
        const int j0 = 32 * pblk + 8 * jj + 4 * hi;
        #pragma unroll
        for (int e = 0; e < 4; ++e) {
          const float vv = ga * rv[4 * jj + e] + kx * px[jj][e];
          Vg[eidx(j0 + e, prow)] = (_Float16)vv;   // V^T
        }
      }
      float m0[8];
      #pragma unroll
      for (int e = 0; e < 8; ++e) m0[e] = fmaxf(fabsf(rv[e]), fabsf(rv[e + 8]));
      #pragma unroll
      for (int e = 0; e < 4; ++e) m0[e] = fmaxf(m0[e], m0[e + 4]);
      float ml = fmaxf(fmaxf(m0[0], m0[1]), fmaxf(m0[2], m0[3]));
      #pragma unroll
      for (int d = 32; d >= 1; d >>= 1) ml = fmaxf(ml, __shfl_xor(ml, d, 64));
      if (lane == 0) red[w] = ml;
    }
    BARX();  // bar1: V, red published

    // ===== REGION2: x gather for s+1, out stores, alpha update, stage1 =====
    if (s + 1 < CL) {
      const float* xp = xsrc + ((size_t)(t0 + s + 1) * NB + b) * 4096 + xoff;
      #pragma unroll
      for (int jj = 0; jj < 4; ++jj) px[jj] = gload4(xp + 8 * jj);
    }
    if constexpr (PASS3) {  // true h^(s) = Sig_old * rv
      if (s > 0) {
        float* oR = out + ((size_t)(t0 + s - 1) * NB + b) * 4096
                        + (grp ? (size_t)NT * NB * 4096 : 0) + (size_t)(prow * 64);
        #pragma unroll
        for (int jj = 0; jj < 4; ++jj) {
          const int j0 = 32 * pblk + 8 * jj + 4 * hi;
          float4_t ov;
          #pragma unroll
          for (int e = 0; e < 4; ++e) ov[e] = Sig * rv[4 * jj + e];
          gstore4(oR + j0, ov);
        }
      }
    }
    Sig *= alphainv;
    {
      float4_t r0 = *(const float4_t*)&red[0];
      float4_t r1 = *(const float4_t*)&red[4];
      float mm = fmaxf(fmaxf(fmaxf(r0[0], r0[1]), fmaxf(r0[2], r0[3])),
                       fmaxf(fmaxf(r1[0], r1[1]), fmaxf(r1[2], r1[3])));
      alpha_from_max(mm, alpha, alphainv);   // stale-1 alpha for next mix
    }

    // ---- stage1: t^T = V^T * U^T ; single hi+lo acc, signs folded into frags ----
    {
      floatx16 ah, al;
      #pragma unroll
      for (int j = 0; j < 16; ++j) { ah[j] = 0.0f; al[j] = 0.0f; }
      #pragma unroll
      for (int kq = 0; kq < 4; ++kq) {
        const int cc = 16 * kq + 8 * hi;
        const int vo = eidx(prow, cc);
        const int uo = uidx(urow, 2 * kq + hi);
        half8 avr = *(const half8*)&Vr[vo];
        half8 avi = *(const half8*)&Vi[vo];
        half8 f0 = grp ? avi : avr;
        half8 f1 = grp ? avr : -avi;
        ah = __builtin_amdgcn_mfma_f32_32x32x16_f16(f0, *(const half8*)&Uhr[uo], ah, 0, 0, 0);
        ah = __builtin_amdgcn_mfma_f32_32x32x16_f16(f1, *(const half8*)&Uhi_[uo], ah, 0, 0, 0);
        al = __builtin_amdgcn_mfma_f32_32x32x16_f16(f0, *(const half8*)&Ulr[uo], al, 0, 0, 0);
        al = __builtin_amdgcn_mfma_f32_32x32x16_f16(f1, *(const half8*)&Uli_[uo], al, 0, 0, 0);
      }
      _Float16* Tg = grp ? Ti : Tr;
      const int tp = 32 * pblk + l31;   // T[p][r]
      #pragma unroll
      for (int jj = 0; jj < 4; ++jj) {
        const int rr0 = 32 * rblk + 8 * jj + 4 * hi;
        half4_t tv;
        #pragma unroll
        for (int e = 0; e < 4; ++e) {
          const int j = 4 * jj + e;
          tv[e] = (_Float16)(ah[j] + al[j] * 0.00390625f);
        }
        *(half4_t*)&Tg[eidx(tp, rr0)] = tv;
      }
    }
    BARX();  // bar2: T published

    // ---- stage2: h'^T = U * t^T -> rv ----
    {
      floatx16 ch, cl;
      #pragma unroll
      for (int j = 0; j < 16; ++j) { ch[j] = 0.0f; cl[j] = 0.0f; }
      const int p2 = 32 * rblk + l31;
      #pragma unroll
      for (int kq = 0; kq < 4; ++kq) {
        const int cc = 16 * kq + 8 * hi;
        const int to = eidx(p2, cc);
        const int uo = uidx(urow, 2 * kq + hi);
        half8 btr = *(const half8*)&Tr[to];
        half8 bti = *(const half8*)&Ti[to];
        half8 f0 = grp ? bti : btr;
        half8 f1 = grp ? -btr : bti;
        ch = __builtin_amdgcn_mfma_f32_32x32x16_f16(*(const half8*)&Uhr[uo], f0, ch, 0, 0, 0);
        ch = __builtin_amdgcn_mfma_f32_32x32x16_f16(*(const half8*)&Uhi_[uo], f1, ch, 0, 0, 0);
        cl = __builtin_amdgcn_mfma_f32_32x32x16_f16(*(const half8*)&Ulr[uo], f0, cl, 0, 0, 0);
        cl = __builtin_amdgcn_mfma_f32_32x32x16_f16(*(const half8*)&Uli_[uo], f1, cl, 0, 0, 0);
      }
      #pragma unroll
      for (int j = 0; j < 16; ++j)
        rv[j] = ch[j] + cl[j] * 0.00390625f;
    }
  }

  // ---- epilogue: direct store of final state (true h = Sig * rv) ----
  {
    const int trow = PASS3 ? (t0 + CL - 1) : t0;
    float* eR = out + ((size_t)trow * NB + b) * 4096
                    + (grp ? (size_t)NT * NB * 4096 : 0) + (size_t)(prow * 64);
    #pragma unroll
    for (int jj = 0; jj < 4; ++jj) {
      const int j0 = 32 * pblk + 8 * jj + 4 * hi;
      float4_t ov;
      #pragma unroll
      for (int e = 0; e < 4; ++e) ov[e] = Sig * rv[4 * jj + e];
      gstore4(eR + j0, ov);
    }
  }
}

// ---------------- K2: W = U^16 (4 LDS squarings) + 7 sequential chunk combines ----
__global__ __launch_bounds__(512, 1)
void qrnn_combine(const float* __restrict__ U_r, const float* __restrict__ U_i,
                  const float* __restrict__ lam_p, float* __restrict__ out) {
  __shared__ float Ga_r[64 * 68], Ga_i[64 * 68], Gb_r[64 * 68], Gb_i[64 * 68];
  __shared__ __align__(16) _Float16 Vr[4096], Vi[4096], Tr[4096], Ti[4096];
  __shared__ float red[8];

  const int b = blockIdx.x;
  const int tid = threadIdx.x;
  const int lane = tid & 63, hi = lane >> 5, l31 = lane & 31, w = tid >> 6;
  const int grp = w >> 2, rblk = (w >> 1) & 1, pblk = w & 1;
  const int prow = 32 * rblk + l31;

  const float g = 1.0f / (1.0f + expf(-lam_p[0]));
  const float g2 = g * g, g4 = g2 * g2, g8 = g4 * g4, g16 = g8 * g8;

  const int qr = tid >> 3, qc = (tid & 7) * 8;
  {
    *(float4_t*)&Ga_r[qr * 68 + qc]     = gload4(U_r + qr * 64 + qc);
    *(float4_t*)&Ga_r[qr * 68 + qc + 4] = gload4(U_r + qr * 64 + qc + 4);
    *(float4_t*)&Ga_i[qr * 68 + qc]     = gload4(U_i + qr * 64 + qc);
    *(float4_t*)&Ga_i[qr * 68 + qc + 4] = gload4(U_i + qr * 64 + qc + 4);
  }
  __syncthreads();

  #pragma unroll
  for (int it = 0; it < 4; ++it) {
    const float* sr = (it & 1) ? Gb_r : Ga_r;
    const float* si = (it & 1) ? Gb_i : Ga_i;
    float* dr = (it & 1) ? Ga_r : Gb_r;
    float* di = (it & 1) ? Ga_i : Gb_i;
    float cr[8], ci[8];
    #pragma unroll
    for (int e = 0; e < 8; ++e) { cr[e] = 0.0f; ci[e] = 0.0f; }
    for (int k = 0; k < 64; ++k) {
      const float ar = sr[qr * 68 + k];
      const float ai = si[qr * 68 + k];
      float4_t br0 = *(const float4_t*)&sr[k * 68 + qc];
      float4_t br1 = *(const float4_t*)&sr[k * 68 + qc + 4];
      float4_t bi0 = *(const float4_t*)&si[k * 68 + qc];
      float4_t bi1 = *(const float4_t*)&si[k * 68 + qc + 4];
      #pragma unroll
      for (int e = 0; e < 4; ++e) {
        cr[e]     += ar * br0[e] - ai * bi0[e];
        ci[e]     += ar * bi0[e] + ai * br0[e];
        cr[4 + e] += ar * br1[e] - ai * bi1[e];
        ci[4 + e] += ar * bi1[e] + ai * br1[e];
      }
    }
    float4_t s0, s1, s2, s3;
    #pragma unroll
    for (int e = 0; e < 4; ++e) { s0[e] = cr[e]; s1[e] = cr[4 + e]; s2[e] = ci[e]; s3[e] = ci[4 + e]; }
    *(float4_t*)&dr[qr * 68 + qc] = s0;  *(float4_t*)&dr[qr * 68 + qc + 4] = s1;
    *(float4_t*)&di[qr * 68 + qc] = s2;  *(float4_t*)&di[qr * 68 + qc + 4] = s3;
    __syncthreads();
  }

  half8 Wrh[4], Wrl[4], Wih[4], Wil[4];
  {
    const int row = 32 * pblk + l31;
    #pragma unroll
    for (int kq = 0; kq < 4; ++kq) {
      const int c0 = 16 * kq + 8 * hi;
      #pragma unroll
      for (int e = 0; e < 8; ++e) {
        const float wr = Ga_r[row * 68 + c0 + e];
        const float wi = Ga_i[row * 68 + c0 + e];
        _Float16 h;
        h = (_Float16)wr; Wrh[kq][e] = h; Wrl[kq][e] = (_Float16)((wr - (float)h) * 256.0f);
        h = (_Float16)wi; Wih[kq][e] = h; Wil[kq][e] = (_Float16)((wi - (float)h) * 256.0f);
      }
    }
  }

  float rv[16];
  #pragma unroll
  for (int j = 0; j < 16; ++j)
    rv[j] = (grp == 0 && prow == jcolf(j, pblk, hi)) ? (1.0f / 64.0f) : 0.0f;

  for (int c = 0; c < NC - 1; ++c) {
    float pv[16];
    {
      const float* ps = out + ((size_t)((grp ? NT : 0) + c * CL) * NB + b) * 4096;
      #pragma unroll
      for (int j = 0; j < 16; ++j) pv[j] = gload1(ps + prow * 64 + jcolf(j, pblk, hi));
    }
    float ml = 0.0f;
    #pragma unroll
    for (int j = 0; j < 16; ++j) ml = fmaxf(ml, fabsf(rv[j]));
    #pragma unroll
    for (int d = 32; d >= 1; d >>= 1) ml = fmaxf(ml, __shfl_xor(ml, d, 64));
    if (lane == 0) red[w] = ml;
    __syncthreads();
    float mm = red[0];
    #pragma unroll
    for (int i = 1; i < 8; ++i) mm = fmaxf(mm, red[i]);
    float al, alinv;
    alpha_from_max(mm, al, alinv);
    const float fE = g16 * alinv;

    {
      _Float16* Vg = grp ? Vi : Vr;
      #pragma unroll
      for (int j = 0; j < 16; ++j)
        Vg[eidx(jcolf(j, pblk, hi), prow)] = (_Float16)(al * rv[j]);
    }
    __syncthreads();

    {
      half8 A0[4], A1[4];
      const int rrow = 32 * rblk + l31;
      #pragma unroll
      for (int kq = 0; kq < 4; ++kq) {
        const int cc = 16 * kq + 8 * hi;
        half8 avr = *(const half8*)&Vr[eidx(rrow, cc)];
        half8 avi = *(const half8*)&Vi[eidx(rrow, cc)];
        if (grp == 0) { A0[kq] = avr; A1[kq] = avi; }
        else          { A0[kq] = avi; A1[kq] = avr; }
      }
      floatx16 a1h, a1l, a2h, a2l;
      #pragma unroll
      for (int j = 0; j < 16; ++j) { a1h[j] = 0; a1l[j] = 0; a2h[j] = 0; a2l[j] = 0; }
      #pragma unroll
      for (int kq = 0; kq < 4; ++kq) {
        a1h = __builtin_amdgcn_mfma_f32_32x32x16_f16(A0[kq], Wrh[kq], a1h, 0, 0, 0);
        a2h = __builtin_amdgcn_mfma_f32_32x32x16_f16(A1[kq], Wih[kq], a2h, 0, 0, 0);
        a1l = __builtin_amdgcn_mfma_f32_32x32x16_f16(A0[kq], Wrl[kq], a1l, 0, 0, 0);
        a2l = __builtin_amdgcn_mfma_f32_32x32x16_f16(A1[kq], Wil[kq], a2l, 0, 0, 0);
      }
      const float s1 = grp ? 1.0f : -1.0f;
      _Float16* Tg = grp ? Ti : Tr;
      const int tp = 32 * pblk + l31;
      #pragma unroll
      for (int jj = 0; jj < 4; ++jj) {
        const int rr0 = 32 * rblk + 8 * jj + 4 * hi;
        half4_t tv;
        #pragma unroll
        for (int e = 0; e < 4; ++e) {
          const int j = 4 * jj + e;
          tv[e] = (_Float16)((a1h[j] + s1 * a2h[j]) + (a1l[j] + s1 * a2l[j]) * 0.00390625f);
        }
        *(half4_t*)&Tg[eidx(tp, rr0)] = tv;
      }
    }
    __syncthreads();

    {
      half8 B0[4], B1[4];
      const int p2 = 32 * rblk + l31;
      #pragma unroll
      for (int kq = 0; kq < 4; ++kq) {
        const int cc = 16 * kq + 8 * hi;
        half8 btr = *(const half8*)&Tr[eidx(p2, cc)];
        half8 bti = *(const half8*)&Ti[eidx(p2, cc)];
        if (grp == 0) { B0[kq] = btr; B1[kq] = bti; }
        else          { B0[kq] = bti; B1[kq] = btr; }
      }
      floatx16 c1h, c1l, c2h, c2l;
      #pragma unroll
      for (int j = 0; j < 16; ++j) { c1h[j] = 0; c1l[j] = 0; c2h[j] = 0; c2l[j] = 0; }
      #pragma unroll
      for (int kq = 0; kq < 4; ++kq) {
        c1h = __builtin_amdgcn_mfma_f32_32x32x16_f16(Wrh[kq], B0[kq], c1h, 0, 0, 0);
        c2h = __builtin_amdgcn_mfma_f32_32x32x16_f16(Wih[kq], B1[kq], c2h, 0, 0, 0);
        c1l = __builtin_amdgcn_mfma_f32_32x32x16_f16(Wrl[kq], B0[kq], c1l, 0, 0, 0);
        c2l = __builtin_amdgcn_mfma_f32_32x32x16_f16(Wil[kq], B1[kq], c2l, 0, 0, 0);
      }
      const float s2 = grp ? -1.0f : 1.0f;
      #pragma unroll
      for (int j = 0; j < 16; ++j) {
        const float rvS = (c1h[j] + s2 * c2h[j]) + (c1l[j] + s2 * c2l[j]) * 0.00390625f;
        rv[j] = fE * rvS + pv[j];
      }
    }
    {
      float* hs = out + ((size_t)((grp ? NT : 0) + (c + 1) * CL + 1) * NB + b) * 4096;
      #pragma unroll
      for (int j = 0; j < 16; ++j) gstore1(hs + prow * 64 + jcolf(j, pblk, hi), rv[j]);
    }
    __syncthreads();
  }
}

extern "C" void kernel_launch(void* const* d_in, const int* in_sizes, int n_in,
                              void* d_out, int out_size, void* d_ws, size_t ws_size,
                              hipStream_t stream) {
  (void)in_sizes; (void)n_in; (void)out_size; (void)d_ws; (void)ws_size;
  const float* dr = (const float*)d_in[0];
  const float* di = (const float*)d_in[1];
  const float* ur = (const float*)d_in[2];
  const float* ui = (const float*)d_in[3];
  const float* lm = (const float*)d_in[4];
  float* o = (float*)d_out;
  qrnn_scan<false><<<dim3(NB * NC), dim3(512), 0, stream>>>(dr, di, ur, ui, lm, o);
  qrnn_combine<<<dim3(NB), dim3(512), 0, stream>>>(ur, ui, lm, o);
  qrnn_scan<true><<<dim3(NB * NC), dim3(512), 0, stream>>>(dr, di, ur, ui, lm, o);
}